// Round 6
// baseline (288.564 us; speedup 1.0000x reference)
//
#include <hip/hip_runtime.h>
#include <math.h>

// ---------------------------------------------------------------------------
// GATPolicy: 3x GATConv (with self loops) + mean-pool + MLP head.
// CSR-by-dst with ZERO global atomics (r1: device-scope atomicAdd bypasses
// the non-coherent XCD L2s; 56us). NOW 3-dispatch CSR (was 5): the explicit
// scanA kernels are gone — histT is only 153KB (8192-edge chunks x 128-node
// buckets), so P3 blocks recompute the bucket-offset scan themselves from
// L2-resident histT (98 coalesced rows + one in-LDS 512-wide scan), and P3
// block 0 publishes prefA[] for P4. Structure:
//   P1  per-block LDS hist over bucket=dst>>7 [fused: transform0 + W pack
//       + gstart boundary scan]
//   P3  partition: self-computed bases; LDS ranks; (src, dst&127) ->
//       bucket-partitioned esrc/dsub8 (~21-edge contiguous segments)
//   P4  one block/bucket (391): LDS count -> 128-scan -> row_ptr -> col
// Ranks arbitrary-but-distinct (order-independent aggregation). n <= 65536.
// AGG (r4/r5): 2 nodes per wave — 32-lane half per node; lane l gathers a
// dword (ch 2l,2l+1 x 2 heads, fp8-interleaved); 32-edge chunks stage
// {w0,w1,rowoff} to wave-private LDS, consume as uniform-per-half broadcasts
// with 8 loads in flight.
// MLP (pool fused, r3 lesson): 512 thr/block, ushort8 pool loads, gstart
// precomputed, fc k-split across thread halves.
// Inter-layer bf16; K=128 transforms via mfma_f32_16x16x32_bf16.
// (r13 lesson: never chain blocks across XCDs.)
// ---------------------------------------------------------------------------

#define LRELU(x) ((x) > 0.f ? (x) : 0.2f * (x))

typedef short bf16x8 __attribute__((ext_vector_type(8)));
typedef unsigned short u16x8 __attribute__((ext_vector_type(8)));
typedef float f32x4 __attribute__((ext_vector_type(4)));
typedef float f32x2 __attribute__((ext_vector_type(2)));

__device__ __forceinline__ unsigned short f2bf(float f) {
    unsigned int u = __float_as_uint(f);
    u = (u + 0x7fffu + ((u >> 16) & 1u)) >> 16;  // RNE
    return (unsigned short)u;
}
__device__ __forceinline__ float bf2f(unsigned short u) {
    return __uint_as_float((unsigned int)u << 16);
}
__device__ __forceinline__ unsigned char f2fp8(float f) {
    return (unsigned char)(__builtin_amdgcn_cvt_pk_fp8_f32(f, f, 0, false) & 0xff);
}
__device__ __forceinline__ f32x2 fp8pair(unsigned int u) {
    return __builtin_amdgcn_cvt_pk_f32_fp8(u, false);  // bytes 0,1
}

// -- P1: bucket hist (8192-edge chunks) || transform0 || W pack || gstart ---

__global__ __launch_bounds__(256) void hist_t0_kernel(
    const int* __restrict__ dst, int* __restrict__ histT,
    int e, int G1, int NB, int n, int hist_blocks, int t0_blocks, int wp_blocks,
    const float* __restrict__ x, const float* __restrict__ W,
    const float* __restrict__ a_src, const float* __restrict__ a_dst,
    unsigned char* __restrict__ h, float* __restrict__ as_o,
    float* __restrict__ ad_o,
    const float* __restrict__ W1, const float* __restrict__ W2,
    unsigned short* __restrict__ Wf1, unsigned short* __restrict__ Wf2,
    const int* __restrict__ batch, int* __restrict__ gstart, int nGraphs) {
    __shared__ unsigned int hist[512];
    __shared__ float xs[2][8][8];
    const int t = threadIdx.x;
    if ((int)blockIdx.x < hist_blocks) {
        hist[t] = 0;
        hist[t + 256] = 0;
        __syncthreads();
        const int g = blockIdx.x;
#pragma unroll
        for (int jj = 0; jj < 8; jj++) {
            int idx = g * 8192 + jj * 1024 + t * 4;
            int d[4];
            if (idx + 4 <= e) {
                int4 dd = *(const int4*)(dst + idx);
                d[0] = dd.x; d[1] = dd.y; d[2] = dd.z; d[3] = dd.w;
            } else {
#pragma unroll
                for (int q = 0; q < 4; q++) d[q] = (idx + q < e) ? dst[idx + q] : -1;
            }
#pragma unroll
            for (int q = 0; q < 4; q++)
                if (d[q] >= 0) atomicAdd(&hist[d[q] >> 7], 1u);
        }
        __syncthreads();
        if (t < NB) histT[g * NB + t] = (int)hist[t];
        if (t + 256 < NB) histT[g * NB + t + 256] = (int)hist[t + 256];
        return;
    }
    if ((int)blockIdx.x < hist_blocks + t0_blocks) {
        // ---- transform0 path: h(fp8)=x@W0, as/ad. 16 nodes/block ----
        const int bid2 = blockIdx.x - hist_blocks;
        const int tid = t & 127;
        const int half = t >> 7;
        const int node0 = bid2 * 16 + half * 8;

        for (int idx = tid; idx < 64; idx += 128) {
            int ni = idx >> 3, k = idx & 7;
            int ng = node0 + ni;
            xs[half][ni][k] = (ng < n) ? x[(size_t)ng * 8 + k] : 0.f;
        }
        __syncthreads();

        float acc[8];
#pragma unroll
        for (int i = 0; i < 8; i++) acc[i] = 0.f;
#pragma unroll
        for (int k = 0; k < 8; k++) {
            float wk = W[k * 128 + tid];
#pragma unroll
            for (int i = 0; i < 8; i++) acc[i] += xs[half][i][k] * wk;
        }

        const int lane = tid & 63;
        const int head = tid >> 6;
        const int pos = 2 * lane + head;  // 2-head interleaved fp8 byte pos
        const float av = a_src[tid];
        const float dv = a_dst[tid];
#pragma unroll
        for (int i = 0; i < 8; i++) {
            int ng = node0 + i;
            if (ng >= n) break;
            h[(size_t)ng * 128 + pos] = f2fp8(acc[i]);
            float ps = acc[i] * av, pd = acc[i] * dv;
            for (int off = 32; off; off >>= 1) {
                ps += __shfl_xor(ps, off, 64);
                pd += __shfl_xor(pd, off, 64);
            }
            if (lane == 0) {
                as_o[ng * 2 + head] = ps;
                ad_o[ng * 2 + head] = pd;
            }
        }
        return;
    }
    if ((int)blockIdx.x < hist_blocks + t0_blocks + wp_blocks) {
        // ---- W pack path ----
        const int n1 = 8 * 4 * 64;   // W1 fragment rows (OUT=128)
        const int n2 = 4 * 4 * 64;   // W2 fragment rows (OUT=64)
        int gid = (blockIdx.x - hist_blocks - t0_blocks) * 256 + t;
        if (gid < n1) {
            int idx = gid;
            int lane = idx & 63, ts = idx >> 6;
            int s = ts & 3, tt = ts >> 2;
            int quad = lane >> 4, cn = lane & 15;
#pragma unroll
            for (int j = 0; j < 8; j++)
                Wf1[idx * 8 + j] = f2bf(W1[(s * 32 + quad * 8 + j) * 128 + tt * 16 + cn]);
        } else if (gid < n1 + n2) {
            int idx = gid - n1;
            int lane = idx & 63, ts = idx >> 6;
            int s = ts & 3, tt = ts >> 2;
            int quad = lane >> 4, cn = lane & 15;
#pragma unroll
            for (int j = 0; j < 8; j++)
                Wf2[idx * 8 + j] = f2bf(W2[(s * 32 + quad * 8 + j) * 64 + tt * 16 + cn]);
        }
        return;
    }
    // ---- gstart path: graph boundaries of sorted batch ----
    int gid = (blockIdx.x - hist_blocks - t0_blocks - wp_blocks) * 256 + t;
    if (gid < n) {
        int bi = batch[gid];
        if (gid == 0) {
            for (int g = 0; g <= bi; g++) gstart[g] = 0;
        } else {
            int bp = batch[gid - 1];
            if (bi != bp)
                for (int g = bp + 1; g <= bi; g++) gstart[g] = gid;
        }
        if (gid == n - 1) {
            for (int g = bi + 1; g <= nGraphs; g++) gstart[g] = n;
        }
    }
}

// -- P3: bucket partition; per-block self-computed offsets (no scan kernels) -
// Block g: column-partials of histT rows < g + column totals + in-LDS
// exclusive scan -> base[b]. Block 0 publishes prefA. Then LDS-rank pass
// writes (src, dst&127) into bucket-partitioned esrc/dsub8.

__global__ __launch_bounds__(256) void bucket_scatter_kernel(
    const int* __restrict__ src, const int* __restrict__ dst,
    const int* __restrict__ histT, int* __restrict__ esrc,
    unsigned char* __restrict__ dsub8, int* __restrict__ prefA,
    int e, int G1, int NB) {
    __shared__ int totL[512], scn[256], prefL[512], baseL[512];
    __shared__ unsigned cnt[512];
    const int t = threadIdx.x;
    const int g = blockIdx.x;

    // column partial (g'<g) and total sums; b = t and b = t+256
    int p0 = 0, tt0 = 0, p1 = 0, tt1 = 0;
    const bool hasHi = (t + 256) < NB;
    for (int g2 = 0; g2 < G1; g2++) {
        int v0 = (t < NB) ? histT[g2 * NB + t] : 0;
        int v1 = hasHi ? histT[g2 * NB + t + 256] : 0;
        if (g2 < g) { p0 += v0; p1 += v1; }
        tt0 += v0; tt1 += v1;
    }
    totL[t] = (t < NB) ? tt0 : 0;
    totL[t + 256] = hasHi ? tt1 : 0;
    __syncthreads();
    // exclusive scan of 512 totals (pair per thread)
    int v0 = totL[2 * t], v1 = totL[2 * t + 1];
    int s = v0 + v1;
    scn[t] = s;
    __syncthreads();
    for (int off = 1; off < 256; off <<= 1) {
        int u = (t >= off) ? scn[t - off] : 0;
        __syncthreads();
        scn[t] += u;
        __syncthreads();
    }
    int base2 = scn[t] - s;
    prefL[2 * t] = base2;
    prefL[2 * t + 1] = base2 + v0;
    __syncthreads();
    baseL[t] = prefL[t] + p0;
    baseL[t + 256] = prefL[t + 256] + p1;
    cnt[t] = 0;
    cnt[t + 256] = 0;
    if (g == 0) {
        if (t < NB) prefA[t] = prefL[t];
        if (hasHi) prefA[t + 256] = prefL[t + 256];
        if (t == 0) prefA[NB] = scn[255];
    }
    __syncthreads();

    // pass2: 8 int4 rounds, LDS ranks, bucket-partitioned writes
#pragma unroll
    for (int jj = 0; jj < 8; jj++) {
        int idx = g * 8192 + jj * 1024 + t * 4;
        int d[4], sv[4];
        if (idx + 4 <= e) {
            int4 dd = *(const int4*)(dst + idx);
            int4 ss = *(const int4*)(src + idx);
            d[0] = dd.x; d[1] = dd.y; d[2] = dd.z; d[3] = dd.w;
            sv[0] = ss.x; sv[1] = ss.y; sv[2] = ss.z; sv[3] = ss.w;
        } else {
#pragma unroll
            for (int q = 0; q < 4; q++) {
                bool v = idx + q < e;
                d[q] = v ? dst[idx + q] : -1;
                sv[q] = v ? src[idx + q] : 0;
            }
        }
        unsigned r[4];
#pragma unroll
        for (int q = 0; q < 4; q++)
            r[q] = (d[q] >= 0) ? atomicAdd(&cnt[d[q] >> 7], 1u) : 0u;
#pragma unroll
        for (int q = 0; q < 4; q++) {
            if (d[q] >= 0) {
                int pos = baseL[d[q] >> 7] + (int)r[q];
                esrc[pos] = sv[q];
                dsub8[pos] = (unsigned char)(d[q] & 127);
            }
        }
    }
}

// -- P4: per-bucket (128 nodes) CSR finalize: count -> scan -> row_ptr -> col

__global__ __launch_bounds__(256) void bucket_csr_kernel(
    const int* __restrict__ prefA, const unsigned char* __restrict__ dsub8,
    const int* __restrict__ esrc, int* __restrict__ row_ptr,
    int* __restrict__ col, int n) {
    __shared__ unsigned int cnt[128];
    __shared__ int rp[128];
    const int t = threadIdx.x;
    const int b = blockIdx.x;
    const int bs = prefA[b];
    const int be = prefA[b + 1];
    if (t < 128) cnt[t] = 0;
    __syncthreads();
    for (int i = bs + t; i < be; i += 256) {
        atomicAdd(&cnt[dsub8[i]], 1u);
    }
    __syncthreads();
    int v = 0;
    if (t < 128) { v = (int)cnt[t]; rp[t] = v; }
    __syncthreads();
    for (int off = 1; off < 128; off <<= 1) {
        int u = (t >= off && t < 128) ? rp[t - off] : 0;
        __syncthreads();
        if (t < 128) rp[t] += u;
        __syncthreads();
    }
    if (t < 128) {
        int excl = rp[t] - v;
        int node = b * 128 + t;
        if (node <= n) row_ptr[node] = bs + excl;  // node==n lands here (E)
        cnt[t] = (unsigned)excl;  // running cursors
    }
    __syncthreads();
    for (int i = bs + t; i < be; i += 256) {
        int sub = dsub8[i];
        unsigned r = atomicAdd(&cnt[sub], 1u);
        col[bs + (int)r] = esrc[i];
    }
}

// fp8 h byte position for channel c: 2-head interleaved pairs, 1-head flat
template <int OUT, int HEADS>
__device__ __forceinline__ int hpos8(int c) {
    return (HEADS == 2) ? (2 * (c & 63) + (c >> 6)) : c;
}

// ---------------- MFMA transform (K=128): h(fp8)=xb(bf16)@W, as/ad ---------

template <int OUT, int HEADS>
__global__ __launch_bounds__(256) void transform_mfma_kernel(
    const unsigned short* __restrict__ xb, const unsigned short* __restrict__ Wf,
    const float* __restrict__ a_src, const float* __restrict__ a_dst,
    unsigned char* __restrict__ h, float* __restrict__ as_o, float* __restrict__ ad_o,
    int n) {
    constexpr int T = OUT / 16, S = 4;  // K = 128
    const int w = threadIdx.x >> 6, lane = threadIdx.x & 63;
    const int node0 = (blockIdx.x * 4 + w) * 16;
    if (node0 >= n) return;
    const int quad = lane >> 4, col = lane & 15;

    const int arow = node0 + col;
    const bool aok = arow < n;
    bf16x8 a[S];
    const unsigned short* xrow = xb + (size_t)arow * 128 + quad * 8;
#pragma unroll
    for (int s = 0; s < S; s++) {
        bf16x8 z = {0, 0, 0, 0, 0, 0, 0, 0};
        a[s] = aok ? *(const bf16x8*)(xrow + s * 32) : z;
    }

    f32x4 acc[T];
#pragma unroll
    for (int t = 0; t < T; t++) acc[t] = (f32x4){0.f, 0.f, 0.f, 0.f};

#pragma unroll
    for (int s = 0; s < S; s++) {
#pragma unroll
        for (int t = 0; t < T; t++) {
            bf16x8 b = *(const bf16x8*)(Wf + ((size_t)(t * S + s) * 64 + lane) * 8);
            acc[t] = __builtin_amdgcn_mfma_f32_16x16x32_bf16(a[s], b, acc[t], 0, 0, 0);
        }
    }

#pragma unroll
    for (int t = 0; t < T; t++) {
        int pos = hpos8<OUT, HEADS>(t * 16 + col);
#pragma unroll
        for (int r = 0; r < 4; r++) {
            int m = node0 + quad * 4 + r;
            if (m < n) h[(size_t)m * OUT + pos] = f2fp8(acc[t][r]);
        }
    }

#pragma unroll
    for (int r = 0; r < 4; r++) {
        float s0 = 0.f, s1 = 0.f, d0 = 0.f, d1 = 0.f;
#pragma unroll
        for (int t = 0; t < T; t++) {
            float av = a_src[t * 16 + col];
            float dv = a_dst[t * 16 + col];
            float v = acc[t][r];
            if (HEADS == 2 && t >= T / 2) { s1 += v * av; d1 += v * dv; }
            else                          { s0 += v * av; d0 += v * dv; }
        }
        for (int off = 8; off; off >>= 1) {
            s0 += __shfl_xor(s0, off, 64);
            d0 += __shfl_xor(d0, off, 64);
            if (HEADS == 2) {
                s1 += __shfl_xor(s1, off, 64);
                d1 += __shfl_xor(d1, off, 64);
            }
        }
        int m = node0 + quad * 4 + r;
        if (m < n) {
            if (HEADS == 2) {
                if (col == 0)      { as_o[m * 2] = s0;     ad_o[m * 2] = d0; }
                else if (col == 1) { as_o[m * 2 + 1] = s1; ad_o[m * 2 + 1] = d1; }
            } else {
                if (col == 0) { as_o[m] = s0; ad_o[m] = d0; }
            }
        }
    }
}

// ------- GAT aggregation, 2 heads (fp8 h): TWO nodes per wave --------------

template <int ACT>  // 1 = elu
__global__ __launch_bounds__(256) void agg2_kernel(
    const int* __restrict__ row_ptr, const int* __restrict__ col,
    const unsigned char* __restrict__ h, const float2* __restrict__ as2,
    const float2* __restrict__ ad2, const float* __restrict__ bias,
    unsigned short* __restrict__ out, int n) {
    __shared__ float w0l[4][2][32], w1l[4][2][32];
    __shared__ unsigned sofl[4][2][32];
    const int w = threadIdx.x >> 6;
    const int lane = threadIdx.x & 63;
    const int half = lane >> 5, l = lane & 31;
    const int node = blockIdx.x * 8 + w * 2 + half;
    const bool active = node < n;

    int beg = 0, deg = 0;
    float2 adv = make_float2(0.f, 0.f);
    float den0 = 0.f, den1 = 0.f;
    float a0 = 0.f, a1 = 0.f, a2 = 0.f, a3 = 0.f;
    if (active) {
        beg = row_ptr[node];
        deg = row_ptr[node + 1] - beg;
        adv = ad2[node];
        float2 avs = as2[node];
        float w0s = __expf(LRELU(avs.x + adv.x));
        float w1s = __expf(LRELU(avs.y + adv.y));
        unsigned us = *(const unsigned*)(h + ((size_t)node << 7) + 4 * l);
        f32x2 p0 = fp8pair(us & 0xffffu);
        f32x2 p1 = fp8pair(us >> 16);
        a0 = w0s * p0.x; a1 = w1s * p0.y;
        a2 = w0s * p1.x; a3 = w1s * p1.y;
        den0 = w0s; den1 = w1s;
    }
    int dmax = deg;
    for (int off = 32; off; off >>= 1) dmax = max(dmax, __shfl_xor(dmax, off, 64));

    for (int base = 0; base < dmax; base += 32) {
        int cnt = deg - base;
        cnt = cnt < 0 ? 0 : (cnt > 32 ? 32 : cnt);
        float w0 = 0.f, w1 = 0.f;
        unsigned so = 0;
        if (l < cnt) {
            int s = col[beg + base + l];
            float2 av = as2[s];
            w0 = __expf(LRELU(av.x + adv.x));
            w1 = __expf(LRELU(av.y + adv.y));
            so = (unsigned)s << 7;
        }
        float t0 = w0, t1 = w1;
        for (int off = 16; off; off >>= 1) {
            t0 += __shfl_xor(t0, off, 64);
            t1 += __shfl_xor(t1, off, 64);
        }
        den0 += t0; den1 += t1;
        w0l[w][half][l] = w0;
        w1l[w][half][l] = w1;
        sofl[w][half][l] = so;

        int jmax = dmax - base;
        jmax = jmax > 32 ? 32 : jmax;
        for (int j = 0; j < jmax; j += 8) {
            unsigned u[8];
#pragma unroll
            for (int k = 0; k < 8; k++) {
                unsigned so_k = sofl[w][half][j + k];
                u[k] = *(const unsigned*)(h + so_k + 4 * l);
            }
            float W0[8], W1[8];
#pragma unroll
            for (int k = 0; k < 8; k++) {
                W0[k] = w0l[w][half][j + k];
                W1[k] = w1l[w][half][j + k];
            }
#pragma unroll
            for (int k = 0; k < 8; k++) {
                f32x2 p0 = fp8pair(u[k] & 0xffffu);
                f32x2 p1 = fp8pair(u[k] >> 16);
                a0 += W0[k] * p0.x; a1 += W1[k] * p0.y;
                a2 += W0[k] * p1.x; a3 += W1[k] * p1.y;
            }
        }
    }

    if (active) {
        float2 bA = *(const float2*)(bias + 2 * l);
        float2 bB = *(const float2*)(bias + 64 + 2 * l);
        float r0 = 1.f / (den0 + 1e-16f), r1 = 1.f / (den1 + 1e-16f);
        float o0 = a0 * r0 + bA.x;
        float o1 = a1 * r1 + bB.x;
        float o2 = a2 * r0 + bA.y;
        float o3 = a3 * r1 + bB.y;
        if (ACT) {
            o0 = o0 > 0.f ? o0 : expm1f(o0);
            o1 = o1 > 0.f ? o1 : expm1f(o1);
            o2 = o2 > 0.f ? o2 : expm1f(o2);
            o3 = o3 > 0.f ? o3 : expm1f(o3);
        }
        unsigned h0 = (unsigned)f2bf(o0) | ((unsigned)f2bf(o2) << 16);
        unsigned h1 = (unsigned)f2bf(o1) | ((unsigned)f2bf(o3) << 16);
        *(unsigned*)(out + (size_t)node * 128 + 2 * l) = h0;
        *(unsigned*)(out + (size_t)node * 128 + 64 + 2 * l) = h1;
    }
}

// ------- GAT aggregation, 1 head (fp8 h, layer 2): two nodes per wave ------

__global__ __launch_bounds__(256) void agg1_kernel(
    const int* __restrict__ row_ptr, const int* __restrict__ col,
    const unsigned char* __restrict__ h, const float* __restrict__ as1,
    const float* __restrict__ ad1, const float* __restrict__ bias,
    unsigned short* __restrict__ out, int n) {
    __shared__ float wl[4][2][32];
    __shared__ unsigned sofl[4][2][32];
    const int w = threadIdx.x >> 6;
    const int lane = threadIdx.x & 63;
    const int half = lane >> 5, l = lane & 31;
    const int node = blockIdx.x * 8 + w * 2 + half;
    const bool active = node < n;

    int beg = 0, deg = 0;
    float adv = 0.f, den = 0.f, a0 = 0.f, a2 = 0.f;
    if (active) {
        beg = row_ptr[node];
        deg = row_ptr[node + 1] - beg;
        adv = ad1[node];
        float ws = __expf(LRELU(as1[node] + adv));
        unsigned us = *(const unsigned short*)(h + ((size_t)node << 6) + 2 * l);
        f32x2 p = fp8pair(us);
        a0 = ws * p.x;
        a2 = ws * p.y;
        den = ws;
    }
    int dmax = deg;
    for (int off = 32; off; off >>= 1) dmax = max(dmax, __shfl_xor(dmax, off, 64));

    for (int base = 0; base < dmax; base += 32) {
        int cnt = deg - base;
        cnt = cnt < 0 ? 0 : (cnt > 32 ? 32 : cnt);
        float w0 = 0.f;
        unsigned so = 0;
        if (l < cnt) {
            int s = col[beg + base + l];
            w0 = __expf(LRELU(as1[s] + adv));
            so = (unsigned)s << 6;
        }
        float t = w0;
        for (int off = 16; off; off >>= 1) t += __shfl_xor(t, off, 64);
        den += t;
        wl[w][half][l] = w0;
        sofl[w][half][l] = so;

        int jmax = dmax - base;
        jmax = jmax > 32 ? 32 : jmax;
        for (int j = 0; j < jmax; j += 8) {
            unsigned u[8];
#pragma unroll
            for (int k = 0; k < 8; k++) {
                unsigned so_k = sofl[w][half][j + k];
                u[k] = *(const unsigned short*)(h + so_k + 2 * l);
            }
            float W0[8];
#pragma unroll
            for (int k = 0; k < 8; k++) W0[k] = wl[w][half][j + k];
#pragma unroll
            for (int k = 0; k < 8; k++) {
                f32x2 p = fp8pair(u[k]);
                a0 += W0[k] * p.x;
                a2 += W0[k] * p.y;
            }
        }
    }

    if (active) {
        float2 bA = *(const float2*)(bias + 2 * l);
        float r = 1.f / (den + 1e-16f);
        float o0 = a0 * r + bA.x;
        float o2 = a2 * r + bA.y;
        unsigned hv = (unsigned)f2bf(o0) | ((unsigned)f2bf(o2) << 16);
        *(unsigned*)(out + (size_t)node * 64 + 2 * l) = hv;
    }
}

// ------- MLP head (pool fused): 512 threads/block, one block per graph -----

__global__ __launch_bounds__(512) void mlp_kernel(
    const unsigned short* __restrict__ xbuf, const int* __restrict__ gstart,
    const float* __restrict__ obs,
    const float* __restrict__ Ws1, const float* __restrict__ bs1,
    const float* __restrict__ ln_g, const float* __restrict__ ln_b,
    const float* __restrict__ Ws2, const float* __restrict__ bs2,
    const float* __restrict__ Wa, const float* __restrict__ ba,
    const float* __restrict__ Wc, const float* __restrict__ bc,
    float* __restrict__ out_logits, float* __restrict__ out_value) {
    int b = blockIdx.x;
    int t = threadIdx.x;
    __shared__ float comb[192];
    __shared__ float red[512];
    __shared__ float red2[8][64];
    __shared__ float hs[256];

    const int gs = gstart[b];
    const int ge = gstart[b + 1];

    // ---- pool: 64 rowgroups (8/wave) x 8 chunks of ushort8 ----
    {
        const int w = t >> 6, lane = t & 63;
        const int rg = w * 8 + (lane >> 3);
        const int sub = lane & 7;
        float acc[8];
#pragma unroll
        for (int j = 0; j < 8; j++) acc[j] = 0.f;
        for (int i = gs + rg; i < ge; i += 64) {
            u16x8 v = *(const u16x8*)(xbuf + (size_t)i * 64 + sub * 8);
#pragma unroll
            for (int j = 0; j < 8; j++) acc[j] += bf2f(v[j]);
        }
#pragma unroll
        for (int off = 8; off <= 32; off <<= 1) {
#pragma unroll
            for (int j = 0; j < 8; j++) acc[j] += __shfl_xor(acc[j], off, 64);
        }
        if (lane < 8) {
#pragma unroll
            for (int j = 0; j < 8; j++) red2[w][lane * 8 + j] = acc[j];
        }
    }
    __syncthreads();
    {
        float cdiv = fmaxf((float)(ge - gs), 1.f);
        if (t < 64) {
            float s = 0.f;
#pragma unroll
            for (int w = 0; w < 8; w++) s += red2[w][t];
            comb[t] = s / cdiv;
        } else if (t < 192) {
            comb[t] = obs[b * 128 + (t - 64)];
        }
    }
    __syncthreads();

    const int t256 = t & 255;
    const int khalf = t >> 8;

    // ---- fc1: k split 2x96 ----
    {
        float accA = 0.f, accB = 0.f;
        int k0 = khalf * 96;
#pragma unroll 4
        for (int k = k0; k < k0 + 96; k += 2) {
            accA += comb[k] * Ws1[k * 256 + t256];
            accB += comb[k + 1] * Ws1[(k + 1) * 256 + t256];
        }
        red[t] = accA + accB;
    }
    __syncthreads();
    float acc = 0.f;
    if (t < 256) acc = bs1[t] + red[t] + red[t + 256];
    __syncthreads();

    // ---- LayerNorm over 256 ----
    red[t] = (t < 256) ? acc : 0.f;
    __syncthreads();
    for (int off = 128; off; off >>= 1) {
        if (t < off) red[t] += red[t + off];
        __syncthreads();
    }
    float mu = red[0] / 256.f;
    __syncthreads();
    float d = acc - mu;
    red[t] = (t < 256) ? d * d : 0.f;
    __syncthreads();
    for (int off = 128; off; off >>= 1) {
        if (t < off) red[t] += red[t + off];
        __syncthreads();
    }
    float var = red[0] / 256.f;
    if (t < 256) {
        float hn = d * rsqrtf(var + 1e-5f) * ln_g[t] + ln_b[t];
        hs[t] = hn > 0.f ? hn : 0.f;
    }
    __syncthreads();

    // ---- fc2: k split 2x128 ----
    {
        float a2A = 0.f, a2B = 0.f;
        int k0 = khalf * 128;
#pragma unroll 4
        for (int k = k0; k < k0 + 128; k += 2) {
            a2A += hs[k] * Ws2[k * 256 + t256];
            a2B += hs[k + 1] * Ws2[(k + 1) * 256 + t256];
        }
        red[t] = a2A + a2B;
    }
    __syncthreads();
    float acc2 = 0.f;
    if (t < 256) {
        acc2 = bs2[t] + red[t] + red[t + 256];
        acc2 = acc2 > 0.f ? acc2 : 0.f;
    }
    __syncthreads();
    if (t < 256) hs[t] = acc2;
    __syncthreads();

    // ---- logits: 16 outs x 32 k-chunks of 8 + LDS tree ----
    {
        int o = t & 15, ck = t >> 4;
        float p = 0.f;
#pragma unroll
        for (int k = 0; k < 8; k++)
            p += hs[ck * 8 + k] * Wa[(ck * 8 + k) * 16 + o];
        red[t] = p;
    }
    __syncthreads();
    for (int off = 16; off >= 1; off >>= 1) {
        if ((t >> 4) < off) red[t] += red[t + off * 16];
        __syncthreads();
    }
    if (t < 16) out_logits[b * 16 + t] = red[t] + ba[t];
    __syncthreads();

    // ---- value: full-width dot + tree over 512 ----
    red[t] = (t < 256) ? hs[t] * Wc[t] : 0.f;
    __syncthreads();
    for (int off = 256; off; off >>= 1) {
        if (t < off) red[t] += red[t + off];
        __syncthreads();
    }
    if (t == 0) out_value[b] = red[0] + bc[0];
}

// ---------------------------------------------------------------------------

extern "C" void kernel_launch(void* const* d_in, const int* in_sizes, int n_in,
                              void* d_out, int out_size, void* d_ws, size_t ws_size,
                              hipStream_t stream) {
    const float* obs    = (const float*)d_in[0];
    const float* nf     = (const float*)d_in[1];
    const int*   ei     = (const int*)d_in[2];
    const int*   batch  = (const int*)d_in[3];
    const float* W0     = (const float*)d_in[4];
    const float* a_src0 = (const float*)d_in[5];
    const float* a_dst0 = (const float*)d_in[6];
    const float* b0     = (const float*)d_in[7];
    const float* W1     = (const float*)d_in[8];
    const float* a_src1 = (const float*)d_in[9];
    const float* a_dst1 = (const float*)d_in[10];
    const float* b1     = (const float*)d_in[11];
    const float* W2     = (const float*)d_in[12];
    const float* a_src2 = (const float*)d_in[13];
    const float* a_dst2 = (const float*)d_in[14];
    const float* b2     = (const float*)d_in[15];
    const float* Ws1    = (const float*)d_in[16];
    const float* bs1    = (const float*)d_in[17];
    const float* ln_g   = (const float*)d_in[18];
    const float* ln_b   = (const float*)d_in[19];
    const float* Ws2    = (const float*)d_in[20];
    const float* bs2    = (const float*)d_in[21];
    const float* Wa     = (const float*)d_in[22];
    const float* ba     = (const float*)d_in[23];
    const float* Wc     = (const float*)d_in[24];
    const float* bc     = (const float*)d_in[25];

    const int N = in_sizes[3];
    const int E = in_sizes[2] / 2;
    const int B = in_sizes[0] / 128;
    const int* src = ei;
    const int* dstp = ei + E;

    // workspace carve (256B aligned)
    char* p = (char*)d_ws;
    auto alloc = [&](size_t bytes) -> void* {
        void* r = (void*)p;
        p += (bytes + 255) & ~(size_t)255;
        return r;
    };
    const int G1 = (E + 8191) / 8192;       // edge chunks (8192/block)
    const int NB = (N + 127) >> 7;          // dst buckets of 128 (n <= 65536)
    int*   row_ptr   = (int*)alloc((size_t)(N + 1) * 4);
    int*   col       = (int*)alloc((size_t)E * 4);
    int*   esrc      = (int*)alloc((size_t)E * 4);           // bucketed src
    unsigned char* dsub8 = (unsigned char*)alloc((size_t)E); // bucketed dst&127
    int*   histT     = (int*)alloc((size_t)G1 * NB * 4);     // [g][b]
    int*   prefA     = (int*)alloc((size_t)(NB + 1) * 4);    // bucket starts
    unsigned char* hbuf = (unsigned char*)alloc((size_t)N * 128);       // fp8
    unsigned short* xb = (unsigned short*)alloc((size_t)N * 128 * 2);   // bf16
    unsigned short* xbuf = (unsigned short*)alloc((size_t)N * 64 * 2);  // bf16
    float* as_       = (float*)alloc((size_t)N * 2 * 4);
    float* ad_       = (float*)alloc((size_t)N * 2 * 4);
    unsigned short* Wf1 = (unsigned short*)alloc((size_t)8 * 4 * 64 * 8 * 2);
    unsigned short* Wf2 = (unsigned short*)alloc((size_t)4 * 4 * 64 * 8 * 2);
    int* gstart      = (int*)alloc((size_t)(B + 1) * 4);

    float* out_logits = (float*)d_out;
    float* out_value  = out_logits + (size_t)B * 16;

    // ---- P1: hist || transform0 || W pack || gstart (1 dispatch) ----
    int t0_blocks = (N + 15) / 16;
    int wp_blocks = (8 * 4 * 64 + 4 * 4 * 64 + 255) / 256;
    int gb_blocks = (N + 255) / 256;
    hist_t0_kernel<<<G1 + t0_blocks + wp_blocks + gb_blocks, 256, 0, stream>>>(
        dstp, histT, E, G1, NB, N, G1, t0_blocks, wp_blocks,
        nf, W0, a_src0, a_dst0, hbuf, as_, ad_,
        W1, W2, Wf1, Wf2, batch, gstart, B);

    // ---- P3 partition (self-computed offsets) + P4 per-bucket finalize ----
    bucket_scatter_kernel<<<G1, 256, 0, stream>>>(
        src, dstp, histT, esrc, dsub8, prefA, E, G1, NB);
    bucket_csr_kernel<<<NB, 256, 0, stream>>>(
        prefA, dsub8, esrc, row_ptr, col, N);

    // ---- GAT layer 0 aggregation (transform fused into P1) ----
    agg2_kernel<1><<<(N + 7) / 8, 256, 0, stream>>>(
        row_ptr, col, hbuf, (const float2*)as_, (const float2*)ad_, b0, xb, N);

    // ---- GAT layer 1: in=128 -> concat, elu (MFMA transform) ----
    transform_mfma_kernel<128, 2><<<(N + 63) / 64, 256, 0, stream>>>(
        xb, Wf1, a_src1, a_dst1, hbuf, as_, ad_, N);
    agg2_kernel<1><<<(N + 7) / 8, 256, 0, stream>>>(
        row_ptr, col, hbuf, (const float2*)as_, (const float2*)ad_, b1, xb, N);

    // ---- GAT layer 2: in=128 -> heads=1, out=64 (MFMA transform) ----
    transform_mfma_kernel<64, 1><<<(N + 63) / 64, 256, 0, stream>>>(
        xb, Wf2, a_src2, a_dst2, hbuf, as_, ad_, N);
    agg1_kernel<<<(N + 7) / 8, 256, 0, stream>>>(
        row_ptr, col, hbuf, as_, ad_, b2, xbuf, N);

    // ---- MLP head with fused mean-pool (1 dispatch, no atomics) ----
    mlp_kernel<<<B, 512, 0, stream>>>(xbuf, gstart, obs, Ws1, bs1, ln_g, ln_b,
                                      Ws2, bs2, Wa, ba, Wc, bc,
                                      out_logits, out_value);
}

// Round 7
// 283.245 us; speedup vs baseline: 1.0188x; 1.0188x over previous
//
#include <hip/hip_runtime.h>
#include <math.h>

// ---------------------------------------------------------------------------
// GATPolicy: 3x GATConv (with self loops) + mean-pool + MLP head.
// CSR-by-dst with ZERO global atomics (r1: device-scope atomicAdd bypasses
// the non-coherent XCD L2s; 56us). 3-dispatch CSR, scan fused into P3.
// r6 lesson: fusing the scan by enlarging chunks to 8192 cut P3 to 98 blocks
// -> 3.6% occupancy -> 49us latency-bound. Fix: SUB-CHUNKED P3 — grid is
// G1 x 4 blocks; block (g,q) owns the q-th 2048-edge quarter of chunk g:
//   phase1  column-partials of histT (g'<g) + totals + in-LDS 512-scan
//           -> baseL[b] (chunk-g segment start per bucket); bid 0 -> prefA
//   phase2  LDS-histogram the preceding quarters (q'<q, <=6144 dst re-reads)
//           directly into the rank counters cnt[b]
//   phase3  rank+scatter own 2048 edges: pos = baseL[b] + atomicAdd(cnt[b])
// Ranks distinct across quarters (each quarter starts at the sum of the
// preceding quarters' counts); arbitrary order is fine (order-independent
// aggregation). n <= 65536. Structure:
//   P1  per-block LDS hist over bucket=dst>>7 (8192-edge chunks) [fused:
//       transform0 + W pack + gstart boundary scan]
//   P3  sub-chunked partition (above) -> esrc/dsub8
//   P4  one block/bucket (128 nodes): LDS count -> scan -> row_ptr -> col
// AGG (r4/r5): 2 nodes per wave — 32-lane half per node; lane l gathers a
// dword (ch 2l,2l+1 x 2 heads, fp8-interleaved); 32-edge chunks stage
// {w0,w1,rowoff} to wave-private LDS, consume as uniform-per-half broadcasts
// with 8 loads in flight.
// MLP (pool fused, r3 lesson): 512 thr/block, ushort8 pool loads, gstart
// precomputed, fc k-split across thread halves.
// Inter-layer bf16; K=128 transforms via mfma_f32_16x16x32_bf16.
// (r13 lesson: never chain blocks across XCDs.)
// ---------------------------------------------------------------------------

#define LRELU(x) ((x) > 0.f ? (x) : 0.2f * (x))

typedef short bf16x8 __attribute__((ext_vector_type(8)));
typedef unsigned short u16x8 __attribute__((ext_vector_type(8)));
typedef float f32x4 __attribute__((ext_vector_type(4)));
typedef float f32x2 __attribute__((ext_vector_type(2)));

__device__ __forceinline__ unsigned short f2bf(float f) {
    unsigned int u = __float_as_uint(f);
    u = (u + 0x7fffu + ((u >> 16) & 1u)) >> 16;  // RNE
    return (unsigned short)u;
}
__device__ __forceinline__ float bf2f(unsigned short u) {
    return __uint_as_float((unsigned int)u << 16);
}
__device__ __forceinline__ unsigned char f2fp8(float f) {
    return (unsigned char)(__builtin_amdgcn_cvt_pk_fp8_f32(f, f, 0, false) & 0xff);
}
__device__ __forceinline__ f32x2 fp8pair(unsigned int u) {
    return __builtin_amdgcn_cvt_pk_f32_fp8(u, false);  // bytes 0,1
}

// -- P1: bucket hist (8192-edge chunks) || transform0 || W pack || gstart ---

__global__ __launch_bounds__(256) void hist_t0_kernel(
    const int* __restrict__ dst, int* __restrict__ histT,
    int e, int G1, int NB, int n, int hist_blocks, int t0_blocks, int wp_blocks,
    const float* __restrict__ x, const float* __restrict__ W,
    const float* __restrict__ a_src, const float* __restrict__ a_dst,
    unsigned char* __restrict__ h, float* __restrict__ as_o,
    float* __restrict__ ad_o,
    const float* __restrict__ W1, const float* __restrict__ W2,
    unsigned short* __restrict__ Wf1, unsigned short* __restrict__ Wf2,
    const int* __restrict__ batch, int* __restrict__ gstart, int nGraphs) {
    __shared__ unsigned int hist[512];
    __shared__ float xs[2][8][8];
    const int t = threadIdx.x;
    if ((int)blockIdx.x < hist_blocks) {
        hist[t] = 0;
        hist[t + 256] = 0;
        __syncthreads();
        const int g = blockIdx.x;
#pragma unroll
        for (int jj = 0; jj < 8; jj++) {
            int idx = g * 8192 + jj * 1024 + t * 4;
            int d[4];
            if (idx + 4 <= e) {
                int4 dd = *(const int4*)(dst + idx);
                d[0] = dd.x; d[1] = dd.y; d[2] = dd.z; d[3] = dd.w;
            } else {
#pragma unroll
                for (int q = 0; q < 4; q++) d[q] = (idx + q < e) ? dst[idx + q] : -1;
            }
#pragma unroll
            for (int q = 0; q < 4; q++)
                if (d[q] >= 0) atomicAdd(&hist[d[q] >> 7], 1u);
        }
        __syncthreads();
        if (t < NB) histT[g * NB + t] = (int)hist[t];
        if (t + 256 < NB) histT[g * NB + t + 256] = (int)hist[t + 256];
        return;
    }
    if ((int)blockIdx.x < hist_blocks + t0_blocks) {
        // ---- transform0 path: h(fp8)=x@W0, as/ad. 16 nodes/block ----
        const int bid2 = blockIdx.x - hist_blocks;
        const int tid = t & 127;
        const int half = t >> 7;
        const int node0 = bid2 * 16 + half * 8;

        for (int idx = tid; idx < 64; idx += 128) {
            int ni = idx >> 3, k = idx & 7;
            int ng = node0 + ni;
            xs[half][ni][k] = (ng < n) ? x[(size_t)ng * 8 + k] : 0.f;
        }
        __syncthreads();

        float acc[8];
#pragma unroll
        for (int i = 0; i < 8; i++) acc[i] = 0.f;
#pragma unroll
        for (int k = 0; k < 8; k++) {
            float wk = W[k * 128 + tid];
#pragma unroll
            for (int i = 0; i < 8; i++) acc[i] += xs[half][i][k] * wk;
        }

        const int lane = tid & 63;
        const int head = tid >> 6;
        const int pos = 2 * lane + head;  // 2-head interleaved fp8 byte pos
        const float av = a_src[tid];
        const float dv = a_dst[tid];
#pragma unroll
        for (int i = 0; i < 8; i++) {
            int ng = node0 + i;
            if (ng >= n) break;
            h[(size_t)ng * 128 + pos] = f2fp8(acc[i]);
            float ps = acc[i] * av, pd = acc[i] * dv;
            for (int off = 32; off; off >>= 1) {
                ps += __shfl_xor(ps, off, 64);
                pd += __shfl_xor(pd, off, 64);
            }
            if (lane == 0) {
                as_o[ng * 2 + head] = ps;
                ad_o[ng * 2 + head] = pd;
            }
        }
        return;
    }
    if ((int)blockIdx.x < hist_blocks + t0_blocks + wp_blocks) {
        // ---- W pack path ----
        const int n1 = 8 * 4 * 64;   // W1 fragment rows (OUT=128)
        const int n2 = 4 * 4 * 64;   // W2 fragment rows (OUT=64)
        int gid = (blockIdx.x - hist_blocks - t0_blocks) * 256 + t;
        if (gid < n1) {
            int idx = gid;
            int lane = idx & 63, ts = idx >> 6;
            int s = ts & 3, tt = ts >> 2;
            int quad = lane >> 4, cn = lane & 15;
#pragma unroll
            for (int j = 0; j < 8; j++)
                Wf1[idx * 8 + j] = f2bf(W1[(s * 32 + quad * 8 + j) * 128 + tt * 16 + cn]);
        } else if (gid < n1 + n2) {
            int idx = gid - n1;
            int lane = idx & 63, ts = idx >> 6;
            int s = ts & 3, tt = ts >> 2;
            int quad = lane >> 4, cn = lane & 15;
#pragma unroll
            for (int j = 0; j < 8; j++)
                Wf2[idx * 8 + j] = f2bf(W2[(s * 32 + quad * 8 + j) * 64 + tt * 16 + cn]);
        }
        return;
    }
    // ---- gstart path: graph boundaries of sorted batch ----
    int gid = (blockIdx.x - hist_blocks - t0_blocks - wp_blocks) * 256 + t;
    if (gid < n) {
        int bi = batch[gid];
        if (gid == 0) {
            for (int g = 0; g <= bi; g++) gstart[g] = 0;
        } else {
            int bp = batch[gid - 1];
            if (bi != bp)
                for (int g = bp + 1; g <= bi; g++) gstart[g] = gid;
        }
        if (gid == n - 1) {
            for (int g = bi + 1; g <= nGraphs; g++) gstart[g] = n;
        }
    }
}

// -- P3: sub-chunked bucket partition; self-computed offsets ----------------
// Block (g = bid>>2, q = bid&3) owns quarter q (2048 edges) of chunk g.

__global__ __launch_bounds__(256) void bucket_scatter_kernel(
    const int* __restrict__ src, const int* __restrict__ dst,
    const int* __restrict__ histT, int* __restrict__ esrc,
    unsigned char* __restrict__ dsub8, int* __restrict__ prefA,
    int e, int G1, int NB) {
    __shared__ int totL[512], scn[256], prefL[512], baseL[512];
    __shared__ unsigned cnt[512];
    const int t = threadIdx.x;
    const int g = blockIdx.x >> 2;
    const int q = blockIdx.x & 3;

    // phase 1: column partial (g'<g) and total sums; b = t and b = t+256
    int p0 = 0, tt0 = 0, p1 = 0, tt1 = 0;
    const bool hasHi = (t + 256) < NB;
    for (int g2 = 0; g2 < G1; g2++) {
        int v0 = (t < NB) ? histT[g2 * NB + t] : 0;
        int v1 = hasHi ? histT[g2 * NB + t + 256] : 0;
        if (g2 < g) { p0 += v0; p1 += v1; }
        tt0 += v0; tt1 += v1;
    }
    totL[t] = (t < NB) ? tt0 : 0;
    totL[t + 256] = hasHi ? tt1 : 0;
    __syncthreads();
    // exclusive scan of 512 totals (pair per thread)
    int v0 = totL[2 * t], v1 = totL[2 * t + 1];
    int s = v0 + v1;
    scn[t] = s;
    __syncthreads();
    for (int off = 1; off < 256; off <<= 1) {
        int u = (t >= off) ? scn[t - off] : 0;
        __syncthreads();
        scn[t] += u;
        __syncthreads();
    }
    int base2 = scn[t] - s;
    prefL[2 * t] = base2;
    prefL[2 * t + 1] = base2 + v0;
    __syncthreads();
    baseL[t] = prefL[t] + p0;
    baseL[t + 256] = prefL[t + 256] + p1;
    cnt[t] = 0;
    cnt[t + 256] = 0;
    if (blockIdx.x == 0) {
        if (t < NB) prefA[t] = prefL[t];
        if (hasHi) prefA[t + 256] = prefL[t + 256];
        if (t == 0) prefA[NB] = scn[255];
    }
    __syncthreads();

    // phase 2: histogram preceding quarters (q'<q) into rank counters
    const int cbase = g * 8192;
    const int pre = q * 2048;
    for (int i = t * 4; i < pre; i += 1024) {
        int idx = cbase + i;
        int d[4];
        if (idx + 4 <= e) {
            int4 dd = *(const int4*)(dst + idx);
            d[0] = dd.x; d[1] = dd.y; d[2] = dd.z; d[3] = dd.w;
        } else {
#pragma unroll
            for (int k = 0; k < 4; k++) d[k] = (idx + k < e) ? dst[idx + k] : -1;
        }
#pragma unroll
        for (int k = 0; k < 4; k++)
            if (d[k] >= 0) atomicAdd(&cnt[d[k] >> 7], 1u);
    }
    __syncthreads();

    // phase 3: rank + scatter own 2048 edges (2 int4 rounds)
#pragma unroll
    for (int jj = 0; jj < 2; jj++) {
        int idx = cbase + pre + jj * 1024 + t * 4;
        int d[4], sv[4];
        if (idx + 4 <= e) {
            int4 dd = *(const int4*)(dst + idx);
            int4 ss = *(const int4*)(src + idx);
            d[0] = dd.x; d[1] = dd.y; d[2] = dd.z; d[3] = dd.w;
            sv[0] = ss.x; sv[1] = ss.y; sv[2] = ss.z; sv[3] = ss.w;
        } else {
#pragma unroll
            for (int k = 0; k < 4; k++) {
                bool v = idx + k < e;
                d[k] = v ? dst[idx + k] : -1;
                sv[k] = v ? src[idx + k] : 0;
            }
        }
        unsigned r[4];
#pragma unroll
        for (int k = 0; k < 4; k++)
            r[k] = (d[k] >= 0) ? atomicAdd(&cnt[d[k] >> 7], 1u) : 0u;
#pragma unroll
        for (int k = 0; k < 4; k++) {
            if (d[k] >= 0) {
                int pos = baseL[d[k] >> 7] + (int)r[k];
                esrc[pos] = sv[k];
                dsub8[pos] = (unsigned char)(d[k] & 127);
            }
        }
    }
}

// -- P4: per-bucket (128 nodes) CSR finalize: count -> scan -> row_ptr -> col

__global__ __launch_bounds__(256) void bucket_csr_kernel(
    const int* __restrict__ prefA, const unsigned char* __restrict__ dsub8,
    const int* __restrict__ esrc, int* __restrict__ row_ptr,
    int* __restrict__ col, int n) {
    __shared__ unsigned int cnt[128];
    __shared__ int rp[128];
    const int t = threadIdx.x;
    const int b = blockIdx.x;
    const int bs = prefA[b];
    const int be = prefA[b + 1];
    if (t < 128) cnt[t] = 0;
    __syncthreads();
    for (int i = bs + t; i < be; i += 256) {
        atomicAdd(&cnt[dsub8[i]], 1u);
    }
    __syncthreads();
    int v = 0;
    if (t < 128) { v = (int)cnt[t]; rp[t] = v; }
    __syncthreads();
    for (int off = 1; off < 128; off <<= 1) {
        int u = (t >= off && t < 128) ? rp[t - off] : 0;
        __syncthreads();
        if (t < 128) rp[t] += u;
        __syncthreads();
    }
    if (t < 128) {
        int excl = rp[t] - v;
        int node = b * 128 + t;
        if (node <= n) row_ptr[node] = bs + excl;  // node==n lands here (E)
        cnt[t] = (unsigned)excl;  // running cursors
    }
    __syncthreads();
    for (int i = bs + t; i < be; i += 256) {
        int sub = dsub8[i];
        unsigned r = atomicAdd(&cnt[sub], 1u);
        col[bs + (int)r] = esrc[i];
    }
}

// fp8 h byte position for channel c: 2-head interleaved pairs, 1-head flat
template <int OUT, int HEADS>
__device__ __forceinline__ int hpos8(int c) {
    return (HEADS == 2) ? (2 * (c & 63) + (c >> 6)) : c;
}

// ---------------- MFMA transform (K=128): h(fp8)=xb(bf16)@W, as/ad ---------

template <int OUT, int HEADS>
__global__ __launch_bounds__(256) void transform_mfma_kernel(
    const unsigned short* __restrict__ xb, const unsigned short* __restrict__ Wf,
    const float* __restrict__ a_src, const float* __restrict__ a_dst,
    unsigned char* __restrict__ h, float* __restrict__ as_o, float* __restrict__ ad_o,
    int n) {
    constexpr int T = OUT / 16, S = 4;  // K = 128
    const int w = threadIdx.x >> 6, lane = threadIdx.x & 63;
    const int node0 = (blockIdx.x * 4 + w) * 16;
    if (node0 >= n) return;
    const int quad = lane >> 4, col = lane & 15;

    const int arow = node0 + col;
    const bool aok = arow < n;
    bf16x8 a[S];
    const unsigned short* xrow = xb + (size_t)arow * 128 + quad * 8;
#pragma unroll
    for (int s = 0; s < S; s++) {
        bf16x8 z = {0, 0, 0, 0, 0, 0, 0, 0};
        a[s] = aok ? *(const bf16x8*)(xrow + s * 32) : z;
    }

    f32x4 acc[T];
#pragma unroll
    for (int t = 0; t < T; t++) acc[t] = (f32x4){0.f, 0.f, 0.f, 0.f};

#pragma unroll
    for (int s = 0; s < S; s++) {
#pragma unroll
        for (int t = 0; t < T; t++) {
            bf16x8 b = *(const bf16x8*)(Wf + ((size_t)(t * S + s) * 64 + lane) * 8);
            acc[t] = __builtin_amdgcn_mfma_f32_16x16x32_bf16(a[s], b, acc[t], 0, 0, 0);
        }
    }

#pragma unroll
    for (int t = 0; t < T; t++) {
        int pos = hpos8<OUT, HEADS>(t * 16 + col);
#pragma unroll
        for (int r = 0; r < 4; r++) {
            int m = node0 + quad * 4 + r;
            if (m < n) h[(size_t)m * OUT + pos] = f2fp8(acc[t][r]);
        }
    }

#pragma unroll
    for (int r = 0; r < 4; r++) {
        float s0 = 0.f, s1 = 0.f, d0 = 0.f, d1 = 0.f;
#pragma unroll
        for (int t = 0; t < T; t++) {
            float av = a_src[t * 16 + col];
            float dv = a_dst[t * 16 + col];
            float v = acc[t][r];
            if (HEADS == 2 && t >= T / 2) { s1 += v * av; d1 += v * dv; }
            else                          { s0 += v * av; d0 += v * dv; }
        }
        for (int off = 8; off; off >>= 1) {
            s0 += __shfl_xor(s0, off, 64);
            d0 += __shfl_xor(d0, off, 64);
            if (HEADS == 2) {
                s1 += __shfl_xor(s1, off, 64);
                d1 += __shfl_xor(d1, off, 64);
            }
        }
        int m = node0 + quad * 4 + r;
        if (m < n) {
            if (HEADS == 2) {
                if (col == 0)      { as_o[m * 2] = s0;     ad_o[m * 2] = d0; }
                else if (col == 1) { as_o[m * 2 + 1] = s1; ad_o[m * 2 + 1] = d1; }
            } else {
                if (col == 0) { as_o[m] = s0; ad_o[m] = d0; }
            }
        }
    }
}

// ------- GAT aggregation, 2 heads (fp8 h): TWO nodes per wave --------------

template <int ACT>  // 1 = elu
__global__ __launch_bounds__(256) void agg2_kernel(
    const int* __restrict__ row_ptr, const int* __restrict__ col,
    const unsigned char* __restrict__ h, const float2* __restrict__ as2,
    const float2* __restrict__ ad2, const float* __restrict__ bias,
    unsigned short* __restrict__ out, int n) {
    __shared__ float w0l[4][2][32], w1l[4][2][32];
    __shared__ unsigned sofl[4][2][32];
    const int w = threadIdx.x >> 6;
    const int lane = threadIdx.x & 63;
    const int half = lane >> 5, l = lane & 31;
    const int node = blockIdx.x * 8 + w * 2 + half;
    const bool active = node < n;

    int beg = 0, deg = 0;
    float2 adv = make_float2(0.f, 0.f);
    float den0 = 0.f, den1 = 0.f;
    float a0 = 0.f, a1 = 0.f, a2 = 0.f, a3 = 0.f;
    if (active) {
        beg = row_ptr[node];
        deg = row_ptr[node + 1] - beg;
        adv = ad2[node];
        float2 avs = as2[node];
        float w0s = __expf(LRELU(avs.x + adv.x));
        float w1s = __expf(LRELU(avs.y + adv.y));
        unsigned us = *(const unsigned*)(h + ((size_t)node << 7) + 4 * l);
        f32x2 p0 = fp8pair(us & 0xffffu);
        f32x2 p1 = fp8pair(us >> 16);
        a0 = w0s * p0.x; a1 = w1s * p0.y;
        a2 = w0s * p1.x; a3 = w1s * p1.y;
        den0 = w0s; den1 = w1s;
    }
    int dmax = deg;
    for (int off = 32; off; off >>= 1) dmax = max(dmax, __shfl_xor(dmax, off, 64));

    for (int base = 0; base < dmax; base += 32) {
        int cnt = deg - base;
        cnt = cnt < 0 ? 0 : (cnt > 32 ? 32 : cnt);
        float w0 = 0.f, w1 = 0.f;
        unsigned so = 0;
        if (l < cnt) {
            int s = col[beg + base + l];
            float2 av = as2[s];
            w0 = __expf(LRELU(av.x + adv.x));
            w1 = __expf(LRELU(av.y + adv.y));
            so = (unsigned)s << 7;
        }
        float t0 = w0, t1 = w1;
        for (int off = 16; off; off >>= 1) {
            t0 += __shfl_xor(t0, off, 64);
            t1 += __shfl_xor(t1, off, 64);
        }
        den0 += t0; den1 += t1;
        w0l[w][half][l] = w0;
        w1l[w][half][l] = w1;
        sofl[w][half][l] = so;

        int jmax = dmax - base;
        jmax = jmax > 32 ? 32 : jmax;
        for (int j = 0; j < jmax; j += 8) {
            unsigned u[8];
#pragma unroll
            for (int k = 0; k < 8; k++) {
                unsigned so_k = sofl[w][half][j + k];
                u[k] = *(const unsigned*)(h + so_k + 4 * l);
            }
            float W0[8], W1[8];
#pragma unroll
            for (int k = 0; k < 8; k++) {
                W0[k] = w0l[w][half][j + k];
                W1[k] = w1l[w][half][j + k];
            }
#pragma unroll
            for (int k = 0; k < 8; k++) {
                f32x2 p0 = fp8pair(u[k] & 0xffffu);
                f32x2 p1 = fp8pair(u[k] >> 16);
                a0 += W0[k] * p0.x; a1 += W1[k] * p0.y;
                a2 += W0[k] * p1.x; a3 += W1[k] * p1.y;
            }
        }
    }

    if (active) {
        float2 bA = *(const float2*)(bias + 2 * l);
        float2 bB = *(const float2*)(bias + 64 + 2 * l);
        float r0 = 1.f / (den0 + 1e-16f), r1 = 1.f / (den1 + 1e-16f);
        float o0 = a0 * r0 + bA.x;
        float o1 = a1 * r1 + bB.x;
        float o2 = a2 * r0 + bA.y;
        float o3 = a3 * r1 + bB.y;
        if (ACT) {
            o0 = o0 > 0.f ? o0 : expm1f(o0);
            o1 = o1 > 0.f ? o1 : expm1f(o1);
            o2 = o2 > 0.f ? o2 : expm1f(o2);
            o3 = o3 > 0.f ? o3 : expm1f(o3);
        }
        unsigned h0 = (unsigned)f2bf(o0) | ((unsigned)f2bf(o2) << 16);
        unsigned h1 = (unsigned)f2bf(o1) | ((unsigned)f2bf(o3) << 16);
        *(unsigned*)(out + (size_t)node * 128 + 2 * l) = h0;
        *(unsigned*)(out + (size_t)node * 128 + 64 + 2 * l) = h1;
    }
}

// ------- GAT aggregation, 1 head (fp8 h, layer 2): two nodes per wave ------

__global__ __launch_bounds__(256) void agg1_kernel(
    const int* __restrict__ row_ptr, const int* __restrict__ col,
    const unsigned char* __restrict__ h, const float* __restrict__ as1,
    const float* __restrict__ ad1, const float* __restrict__ bias,
    unsigned short* __restrict__ out, int n) {
    __shared__ float wl[4][2][32];
    __shared__ unsigned sofl[4][2][32];
    const int w = threadIdx.x >> 6;
    const int lane = threadIdx.x & 63;
    const int half = lane >> 5, l = lane & 31;
    const int node = blockIdx.x * 8 + w * 2 + half;
    const bool active = node < n;

    int beg = 0, deg = 0;
    float adv = 0.f, den = 0.f, a0 = 0.f, a2 = 0.f;
    if (active) {
        beg = row_ptr[node];
        deg = row_ptr[node + 1] - beg;
        adv = ad1[node];
        float ws = __expf(LRELU(as1[node] + adv));
        unsigned us = *(const unsigned short*)(h + ((size_t)node << 6) + 2 * l);
        f32x2 p = fp8pair(us);
        a0 = ws * p.x;
        a2 = ws * p.y;
        den = ws;
    }
    int dmax = deg;
    for (int off = 32; off; off >>= 1) dmax = max(dmax, __shfl_xor(dmax, off, 64));

    for (int base = 0; base < dmax; base += 32) {
        int cnt = deg - base;
        cnt = cnt < 0 ? 0 : (cnt > 32 ? 32 : cnt);
        float w0 = 0.f;
        unsigned so = 0;
        if (l < cnt) {
            int s = col[beg + base + l];
            w0 = __expf(LRELU(as1[s] + adv));
            so = (unsigned)s << 6;
        }
        float t = w0;
        for (int off = 16; off; off >>= 1) t += __shfl_xor(t, off, 64);
        den += t;
        wl[w][half][l] = w0;
        sofl[w][half][l] = so;

        int jmax = dmax - base;
        jmax = jmax > 32 ? 32 : jmax;
        for (int j = 0; j < jmax; j += 8) {
            unsigned u[8];
#pragma unroll
            for (int k = 0; k < 8; k++) {
                unsigned so_k = sofl[w][half][j + k];
                u[k] = *(const unsigned short*)(h + so_k + 2 * l);
            }
            float W0[8];
#pragma unroll
            for (int k = 0; k < 8; k++) W0[k] = wl[w][half][j + k];
#pragma unroll
            for (int k = 0; k < 8; k++) {
                f32x2 p = fp8pair(u[k]);
                a0 += W0[k] * p.x;
                a2 += W0[k] * p.y;
            }
        }
    }

    if (active) {
        float2 bA = *(const float2*)(bias + 2 * l);
        float r = 1.f / (den + 1e-16f);
        float o0 = a0 * r + bA.x;
        float o2 = a2 * r + bA.y;
        unsigned hv = (unsigned)f2bf(o0) | ((unsigned)f2bf(o2) << 16);
        *(unsigned*)(out + (size_t)node * 64 + 2 * l) = hv;
    }
}

// ------- MLP head (pool fused): 512 threads/block, one block per graph -----

__global__ __launch_bounds__(512) void mlp_kernel(
    const unsigned short* __restrict__ xbuf, const int* __restrict__ gstart,
    const float* __restrict__ obs,
    const float* __restrict__ Ws1, const float* __restrict__ bs1,
    const float* __restrict__ ln_g, const float* __restrict__ ln_b,
    const float* __restrict__ Ws2, const float* __restrict__ bs2,
    const float* __restrict__ Wa, const float* __restrict__ ba,
    const float* __restrict__ Wc, const float* __restrict__ bc,
    float* __restrict__ out_logits, float* __restrict__ out_value) {
    int b = blockIdx.x;
    int t = threadIdx.x;
    __shared__ float comb[192];
    __shared__ float red[512];
    __shared__ float red2[8][64];
    __shared__ float hs[256];

    const int gs = gstart[b];
    const int ge = gstart[b + 1];

    // ---- pool: 64 rowgroups (8/wave) x 8 chunks of ushort8 ----
    {
        const int w = t >> 6, lane = t & 63;
        const int rg = w * 8 + (lane >> 3);
        const int sub = lane & 7;
        float acc[8];
#pragma unroll
        for (int j = 0; j < 8; j++) acc[j] = 0.f;
        for (int i = gs + rg; i < ge; i += 64) {
            u16x8 v = *(const u16x8*)(xbuf + (size_t)i * 64 + sub * 8);
#pragma unroll
            for (int j = 0; j < 8; j++) acc[j] += bf2f(v[j]);
        }
#pragma unroll
        for (int off = 8; off <= 32; off <<= 1) {
#pragma unroll
            for (int j = 0; j < 8; j++) acc[j] += __shfl_xor(acc[j], off, 64);
        }
        if (lane < 8) {
#pragma unroll
            for (int j = 0; j < 8; j++) red2[w][lane * 8 + j] = acc[j];
        }
    }
    __syncthreads();
    {
        float cdiv = fmaxf((float)(ge - gs), 1.f);
        if (t < 64) {
            float s = 0.f;
#pragma unroll
            for (int w = 0; w < 8; w++) s += red2[w][t];
            comb[t] = s / cdiv;
        } else if (t < 192) {
            comb[t] = obs[b * 128 + (t - 64)];
        }
    }
    __syncthreads();

    const int t256 = t & 255;
    const int khalf = t >> 8;

    // ---- fc1: k split 2x96 ----
    {
        float accA = 0.f, accB = 0.f;
        int k0 = khalf * 96;
#pragma unroll 4
        for (int k = k0; k < k0 + 96; k += 2) {
            accA += comb[k] * Ws1[k * 256 + t256];
            accB += comb[k + 1] * Ws1[(k + 1) * 256 + t256];
        }
        red[t] = accA + accB;
    }
    __syncthreads();
    float acc = 0.f;
    if (t < 256) acc = bs1[t] + red[t] + red[t + 256];
    __syncthreads();

    // ---- LayerNorm over 256 ----
    red[t] = (t < 256) ? acc : 0.f;
    __syncthreads();
    for (int off = 128; off; off >>= 1) {
        if (t < off) red[t] += red[t + off];
        __syncthreads();
    }
    float mu = red[0] / 256.f;
    __syncthreads();
    float d = acc - mu;
    red[t] = (t < 256) ? d * d : 0.f;
    __syncthreads();
    for (int off = 128; off; off >>= 1) {
        if (t < off) red[t] += red[t + off];
        __syncthreads();
    }
    float var = red[0] / 256.f;
    if (t < 256) {
        float hn = d * rsqrtf(var + 1e-5f) * ln_g[t] + ln_b[t];
        hs[t] = hn > 0.f ? hn : 0.f;
    }
    __syncthreads();

    // ---- fc2: k split 2x128 ----
    {
        float a2A = 0.f, a2B = 0.f;
        int k0 = khalf * 128;
#pragma unroll 4
        for (int k = k0; k < k0 + 128; k += 2) {
            a2A += hs[k] * Ws2[k * 256 + t256];
            a2B += hs[k + 1] * Ws2[(k + 1) * 256 + t256];
        }
        red[t] = a2A + a2B;
    }
    __syncthreads();
    float acc2 = 0.f;
    if (t < 256) {
        acc2 = bs2[t] + red[t] + red[t + 256];
        acc2 = acc2 > 0.f ? acc2 : 0.f;
    }
    __syncthreads();
    if (t < 256) hs[t] = acc2;
    __syncthreads();

    // ---- logits: 16 outs x 32 k-chunks of 8 + LDS tree ----
    {
        int o = t & 15, ck = t >> 4;
        float p = 0.f;
#pragma unroll
        for (int k = 0; k < 8; k++)
            p += hs[ck * 8 + k] * Wa[(ck * 8 + k) * 16 + o];
        red[t] = p;
    }
    __syncthreads();
    for (int off = 16; off >= 1; off >>= 1) {
        if ((t >> 4) < off) red[t] += red[t + off * 16];
        __syncthreads();
    }
    if (t < 16) out_logits[b * 16 + t] = red[t] + ba[t];
    __syncthreads();

    // ---- value: full-width dot + tree over 512 ----
    red[t] = (t < 256) ? hs[t] * Wc[t] : 0.f;
    __syncthreads();
    for (int off = 256; off; off >>= 1) {
        if (t < off) red[t] += red[t + off];
        __syncthreads();
    }
    if (t == 0) out_value[b] = red[0] + bc[0];
}

// ---------------------------------------------------------------------------

extern "C" void kernel_launch(void* const* d_in, const int* in_sizes, int n_in,
                              void* d_out, int out_size, void* d_ws, size_t ws_size,
                              hipStream_t stream) {
    const float* obs    = (const float*)d_in[0];
    const float* nf     = (const float*)d_in[1];
    const int*   ei     = (const int*)d_in[2];
    const int*   batch  = (const int*)d_in[3];
    const float* W0     = (const float*)d_in[4];
    const float* a_src0 = (const float*)d_in[5];
    const float* a_dst0 = (const float*)d_in[6];
    const float* b0     = (const float*)d_in[7];
    const float* W1     = (const float*)d_in[8];
    const float* a_src1 = (const float*)d_in[9];
    const float* a_dst1 = (const float*)d_in[10];
    const float* b1     = (const float*)d_in[11];
    const float* W2     = (const float*)d_in[12];
    const float* a_src2 = (const float*)d_in[13];
    const float* a_dst2 = (const float*)d_in[14];
    const float* b2     = (const float*)d_in[15];
    const float* Ws1    = (const float*)d_in[16];
    const float* bs1    = (const float*)d_in[17];
    const float* ln_g   = (const float*)d_in[18];
    const float* ln_b   = (const float*)d_in[19];
    const float* Ws2    = (const float*)d_in[20];
    const float* bs2    = (const float*)d_in[21];
    const float* Wa     = (const float*)d_in[22];
    const float* ba     = (const float*)d_in[23];
    const float* Wc     = (const float*)d_in[24];
    const float* bc     = (const float*)d_in[25];

    const int N = in_sizes[3];
    const int E = in_sizes[2] / 2;
    const int B = in_sizes[0] / 128;
    const int* src = ei;
    const int* dstp = ei + E;

    // workspace carve (256B aligned)
    char* p = (char*)d_ws;
    auto alloc = [&](size_t bytes) -> void* {
        void* r = (void*)p;
        p += (bytes + 255) & ~(size_t)255;
        return r;
    };
    const int G1 = (E + 8191) / 8192;       // edge chunks (8192/chunk)
    const int NB = (N + 127) >> 7;          // dst buckets of 128 (n <= 65536)
    int*   row_ptr   = (int*)alloc((size_t)(N + 1) * 4);
    int*   col       = (int*)alloc((size_t)E * 4);
    int*   esrc      = (int*)alloc((size_t)E * 4);           // bucketed src
    unsigned char* dsub8 = (unsigned char*)alloc((size_t)E); // bucketed dst&127
    int*   histT     = (int*)alloc((size_t)G1 * NB * 4);     // [g][b]
    int*   prefA     = (int*)alloc((size_t)(NB + 1) * 4);    // bucket starts
    unsigned char* hbuf = (unsigned char*)alloc((size_t)N * 128);       // fp8
    unsigned short* xb = (unsigned short*)alloc((size_t)N * 128 * 2);   // bf16
    unsigned short* xbuf = (unsigned short*)alloc((size_t)N * 64 * 2);  // bf16
    float* as_       = (float*)alloc((size_t)N * 2 * 4);
    float* ad_       = (float*)alloc((size_t)N * 2 * 4);
    unsigned short* Wf1 = (unsigned short*)alloc((size_t)8 * 4 * 64 * 8 * 2);
    unsigned short* Wf2 = (unsigned short*)alloc((size_t)4 * 4 * 64 * 8 * 2);
    int* gstart      = (int*)alloc((size_t)(B + 1) * 4);

    float* out_logits = (float*)d_out;
    float* out_value  = out_logits + (size_t)B * 16;

    // ---- P1: hist || transform0 || W pack || gstart (1 dispatch) ----
    int t0_blocks = (N + 15) / 16;
    int wp_blocks = (8 * 4 * 64 + 4 * 4 * 64 + 255) / 256;
    int gb_blocks = (N + 255) / 256;
    hist_t0_kernel<<<G1 + t0_blocks + wp_blocks + gb_blocks, 256, 0, stream>>>(
        dstp, histT, E, G1, NB, N, G1, t0_blocks, wp_blocks,
        nf, W0, a_src0, a_dst0, hbuf, as_, ad_,
        W1, W2, Wf1, Wf2, batch, gstart, B);

    // ---- P3 sub-chunked partition (4 blocks/chunk) + P4 finalize ----
    bucket_scatter_kernel<<<G1 * 4, 256, 0, stream>>>(
        src, dstp, histT, esrc, dsub8, prefA, E, G1, NB);
    bucket_csr_kernel<<<NB, 256, 0, stream>>>(
        prefA, dsub8, esrc, row_ptr, col, N);

    // ---- GAT layer 0 aggregation (transform fused into P1) ----
    agg2_kernel<1><<<(N + 7) / 8, 256, 0, stream>>>(
        row_ptr, col, hbuf, (const float2*)as_, (const float2*)ad_, b0, xb, N);

    // ---- GAT layer 1: in=128 -> concat, elu (MFMA transform) ----
    transform_mfma_kernel<128, 2><<<(N + 63) / 64, 256, 0, stream>>>(
        xb, Wf1, a_src1, a_dst1, hbuf, as_, ad_, N);
    agg2_kernel<1><<<(N + 7) / 8, 256, 0, stream>>>(
        row_ptr, col, hbuf, (const float2*)as_, (const float2*)ad_, b1, xb, N);

    // ---- GAT layer 2: in=128 -> heads=1, out=64 (MFMA transform) ----
    transform_mfma_kernel<64, 1><<<(N + 63) / 64, 256, 0, stream>>>(
        xb, Wf2, a_src2, a_dst2, hbuf, as_, ad_, N);
    agg1_kernel<<<(N + 7) / 8, 256, 0, stream>>>(
        row_ptr, col, hbuf, as_, ad_, b2, xbuf, N);

    // ---- MLP head with fused mean-pool (1 dispatch, no atomics) ----
    mlp_kernel<<<B, 512, 0, stream>>>(xbuf, gstart, obs, Ws1, bs1, ln_g, ln_b,
                                      Ws2, bs2, Wa, ba, Wc, bc,
                                      out_logits, out_value);
}

// Round 8
// 262.139 us; speedup vs baseline: 1.1008x; 1.0805x over previous
//
#include <hip/hip_runtime.h>
#include <math.h>

// ---------------------------------------------------------------------------
// GATPolicy: 3x GATConv (with self loops) + mean-pool + MLP head.
// CSR-by-dst with ZERO global atomics (r1: device-scope atomicAdd bypasses
// the non-coherent XCD L2s; 56us). r6/r7 lesson: fusing the offs-scan into
// P3 (redundant per-block recompute of a 98x512 column scan) is latency-
// dominated at any occupancy (48us, VGPR-starved serial L3 chain) and
// sub-chunking shrinks write segments below line size (WRITE 3x). REVERTED
// to the r5 structure (265us): explicit tiny scan dispatches + 2048-edge
// scatter blocks; NEW: scatter caches its offs column (196 ints) in LDS —
// the per-edge offs lookup was ~800k random global reads, now LDS.
//   P1    per-block LDS hist over bucket=dst>>8 (2048-edge chunks) [fused:
//         transform0 + W pack + gstart boundary scan]
//   scanA histT[b*G1+g] -> offs (2 small dispatches, 512 elems/block)
//   P3    partition: LDS ranks + LDS-cached offs col -> esrc/dsub8
//   P4    one block/bucket (256 nodes): LDS count -> scan -> row_ptr -> col
// Ranks arbitrary-but-distinct (order-independent aggregation). n <= 65536.
// AGG (r4/r5): 2 nodes per wave — 32-lane half per node; lane l gathers a
// dword (ch 2l,2l+1 x 2 heads, fp8-interleaved); 32-edge chunks stage
// {w0,w1,rowoff} to wave-private LDS, consume as uniform-per-half broadcasts
// with 8 loads in flight.
// MLP (pool fused, r3 lesson): 512 thr/block, ushort8 pool loads, gstart
// precomputed, fc k-split across thread halves.
// Inter-layer bf16; K=128 transforms via mfma_f32_16x16x32_bf16.
// (r13 lesson: never chain blocks across XCDs.)
// ---------------------------------------------------------------------------

#define LRELU(x) ((x) > 0.f ? (x) : 0.2f * (x))

typedef short bf16x8 __attribute__((ext_vector_type(8)));
typedef unsigned short u16x8 __attribute__((ext_vector_type(8)));
typedef float f32x4 __attribute__((ext_vector_type(4)));
typedef float f32x2 __attribute__((ext_vector_type(2)));

__device__ __forceinline__ unsigned short f2bf(float f) {
    unsigned int u = __float_as_uint(f);
    u = (u + 0x7fffu + ((u >> 16) & 1u)) >> 16;  // RNE
    return (unsigned short)u;
}
__device__ __forceinline__ float bf2f(unsigned short u) {
    return __uint_as_float((unsigned int)u << 16);
}
__device__ __forceinline__ unsigned char f2fp8(float f) {
    return (unsigned char)(__builtin_amdgcn_cvt_pk_fp8_f32(f, f, 0, false) & 0xff);
}
__device__ __forceinline__ f32x2 fp8pair(unsigned int u) {
    return __builtin_amdgcn_cvt_pk_f32_fp8(u, false);  // bytes 0,1
}

// -- P1: bucket hist (2048-edge chunks) || transform0 || W pack || gstart ---

__global__ __launch_bounds__(256) void hist_t0_kernel(
    const int* __restrict__ dst, int* __restrict__ histT,
    int e, int G1, int NB, int n, int hist_blocks, int t0_blocks, int wp_blocks,
    const float* __restrict__ x, const float* __restrict__ W,
    const float* __restrict__ a_src, const float* __restrict__ a_dst,
    unsigned char* __restrict__ h, float* __restrict__ as_o,
    float* __restrict__ ad_o,
    const float* __restrict__ W1, const float* __restrict__ W2,
    unsigned short* __restrict__ Wf1, unsigned short* __restrict__ Wf2,
    const int* __restrict__ batch, int* __restrict__ gstart, int nGraphs) {
    __shared__ unsigned int hist[256];
    __shared__ float xs[2][8][8];
    const int t = threadIdx.x;
    if ((int)blockIdx.x < hist_blocks) {
        hist[t] = 0;
        __syncthreads();
        int base = blockIdx.x * 2048 + t * 8;
        int d[8];
        if (base + 8 <= e) {
            int4 x0 = *(const int4*)(dst + base);
            int4 x1 = *(const int4*)(dst + base + 4);
            d[0] = x0.x; d[1] = x0.y; d[2] = x0.z; d[3] = x0.w;
            d[4] = x1.x; d[5] = x1.y; d[6] = x1.z; d[7] = x1.w;
        } else {
#pragma unroll
            for (int j = 0; j < 8; j++) {
                int ij = base + j;
                d[j] = (ij < e) ? dst[ij] : -1;
            }
        }
#pragma unroll
        for (int j = 0; j < 8; j++) {
            if (d[j] >= 0) atomicAdd(&hist[d[j] >> 8], 1u);
        }
        __syncthreads();
        if (t < NB) histT[t * G1 + blockIdx.x] = (int)hist[t];
        return;
    }
    if ((int)blockIdx.x < hist_blocks + t0_blocks) {
        // ---- transform0 path: h(fp8)=x@W0, as/ad. 16 nodes/block ----
        const int bid2 = blockIdx.x - hist_blocks;
        const int tid = t & 127;
        const int half = t >> 7;
        const int node0 = bid2 * 16 + half * 8;

        for (int idx = tid; idx < 64; idx += 128) {
            int ni = idx >> 3, k = idx & 7;
            int ng = node0 + ni;
            xs[half][ni][k] = (ng < n) ? x[(size_t)ng * 8 + k] : 0.f;
        }
        __syncthreads();

        float acc[8];
#pragma unroll
        for (int i = 0; i < 8; i++) acc[i] = 0.f;
#pragma unroll
        for (int k = 0; k < 8; k++) {
            float wk = W[k * 128 + tid];
#pragma unroll
            for (int i = 0; i < 8; i++) acc[i] += xs[half][i][k] * wk;
        }

        const int lane = tid & 63;
        const int head = tid >> 6;
        const int pos = 2 * lane + head;  // 2-head interleaved fp8 byte pos
        const float av = a_src[tid];
        const float dv = a_dst[tid];
#pragma unroll
        for (int i = 0; i < 8; i++) {
            int ng = node0 + i;
            if (ng >= n) break;
            h[(size_t)ng * 128 + pos] = f2fp8(acc[i]);
            float ps = acc[i] * av, pd = acc[i] * dv;
            for (int off = 32; off; off >>= 1) {
                ps += __shfl_xor(ps, off, 64);
                pd += __shfl_xor(pd, off, 64);
            }
            if (lane == 0) {
                as_o[ng * 2 + head] = ps;
                ad_o[ng * 2 + head] = pd;
            }
        }
        return;
    }
    if ((int)blockIdx.x < hist_blocks + t0_blocks + wp_blocks) {
        // ---- W pack path ----
        const int n1 = 8 * 4 * 64;   // W1 fragment rows (OUT=128)
        const int n2 = 4 * 4 * 64;   // W2 fragment rows (OUT=64)
        int gid = (blockIdx.x - hist_blocks - t0_blocks) * 256 + t;
        if (gid < n1) {
            int idx = gid;
            int lane = idx & 63, ts = idx >> 6;
            int s = ts & 3, tt = ts >> 2;
            int quad = lane >> 4, cn = lane & 15;
#pragma unroll
            for (int j = 0; j < 8; j++)
                Wf1[idx * 8 + j] = f2bf(W1[(s * 32 + quad * 8 + j) * 128 + tt * 16 + cn]);
        } else if (gid < n1 + n2) {
            int idx = gid - n1;
            int lane = idx & 63, ts = idx >> 6;
            int s = ts & 3, tt = ts >> 2;
            int quad = lane >> 4, cn = lane & 15;
#pragma unroll
            for (int j = 0; j < 8; j++)
                Wf2[idx * 8 + j] = f2bf(W2[(s * 32 + quad * 8 + j) * 64 + tt * 16 + cn]);
        }
        return;
    }
    // ---- gstart path: graph boundaries of sorted batch ----
    int gid = (blockIdx.x - hist_blocks - t0_blocks - wp_blocks) * 256 + t;
    if (gid < n) {
        int bi = batch[gid];
        if (gid == 0) {
            for (int g = 0; g <= bi; g++) gstart[g] = 0;
        } else {
            int bp = batch[gid - 1];
            if (bi != bp)
                for (int g = bp + 1; g <= bi; g++) gstart[g] = gid;
        }
        if (gid == n - 1) {
            for (int g = bi + 1; g <= nGraphs; g++) gstart[g] = n;
        }
    }
}

// ---------------- generalized scan: 512 elements per block -----------------

__global__ __launch_bounds__(256) void scan2_block_kernel(
    const int* __restrict__ in, int* __restrict__ out,
    int* __restrict__ blockSums, int len) {
    __shared__ int lds[256];
    int t = threadIdx.x;
    int i0 = blockIdx.x * 512 + 2 * t;
    int v0 = (i0 < len) ? in[i0] : 0;
    int v1 = (i0 + 1 < len) ? in[i0 + 1] : 0;
    int s = v0 + v1;
    lds[t] = s;
    __syncthreads();
    for (int off = 1; off < 256; off <<= 1) {
        int u = (t >= off) ? lds[t - off] : 0;
        __syncthreads();
        lds[t] += u;
        __syncthreads();
    }
    int base = lds[t] - s;  // block-local exclusive for element i0
    if (i0 < len) out[i0] = base;
    if (i0 + 1 < len) out[i0 + 1] = base + v0;
    if (t == 255) blockSums[blockIdx.x] = lds[255];
}

// Every block redundantly scans blockSums (nb <= 256) and applies its base.
// Also writes out[len] = total.
__global__ __launch_bounds__(256) void scan2_finalize_kernel(
    int* __restrict__ out, const int* __restrict__ blockSums, int len, int nb) {
    __shared__ int lds[256];
    int t = threadIdx.x;
    int v = (t < nb) ? blockSums[t] : 0;
    lds[t] = v;
    __syncthreads();
    for (int off = 1; off < 256; off <<= 1) {
        int u = (t >= off) ? lds[t - off] : 0;
        __syncthreads();
        lds[t] += u;
        __syncthreads();
    }
    const int bid = blockIdx.x;
    const int base = (bid > 0) ? lds[bid - 1] : 0;
    const int total = lds[nb - 1];
    int i0 = bid * 512 + 2 * t;
#pragma unroll
    for (int q = 0; q < 2; q++) {
        int i = i0 + q;
        if (i < len) out[i] += base;
        else if (i == len) out[len] = total;
    }
}

// -- P3: bucket partition (LDS ranks; offs column cached in LDS) ------------

__global__ __launch_bounds__(256) void bucket_scatter_kernel(
    const int* __restrict__ src, const int* __restrict__ dst,
    const int* __restrict__ offs, int* __restrict__ esrc,
    unsigned char* __restrict__ dsub8, int e, int G1, int NB) {
    __shared__ unsigned int hist[256];
    __shared__ int baseL[256];
    const int t = threadIdx.x;
    hist[t] = 0;
    if (t < NB) baseL[t] = offs[t * G1 + blockIdx.x];
    __syncthreads();
    int base = blockIdx.x * 2048 + t * 8;
    int d[8], s[8];
    if (base + 8 <= e) {
        int4 d0 = *(const int4*)(dst + base);
        int4 d1 = *(const int4*)(dst + base + 4);
        int4 s0 = *(const int4*)(src + base);
        int4 s1 = *(const int4*)(src + base + 4);
        d[0] = d0.x; d[1] = d0.y; d[2] = d0.z; d[3] = d0.w;
        d[4] = d1.x; d[5] = d1.y; d[6] = d1.z; d[7] = d1.w;
        s[0] = s0.x; s[1] = s0.y; s[2] = s0.z; s[3] = s0.w;
        s[4] = s1.x; s[5] = s1.y; s[6] = s1.z; s[7] = s1.w;
    } else {
#pragma unroll
        for (int j = 0; j < 8; j++) {
            int ij = base + j;
            bool v = ij < e;
            d[j] = v ? dst[ij] : -1;
            s[j] = v ? src[ij] : 0;
        }
    }
    unsigned lr[8];
#pragma unroll
    for (int j = 0; j < 8; j++) {
        lr[j] = (d[j] >= 0) ? atomicAdd(&hist[d[j] >> 8], 1u) : 0u;
    }
#pragma unroll
    for (int j = 0; j < 8; j++) {
        if (d[j] >= 0) {
            int pos = baseL[d[j] >> 8] + (int)lr[j];
            esrc[pos] = s[j];
            dsub8[pos] = (unsigned char)(d[j] & 255);
        }
    }
}

// -- P4: per-bucket (256 nodes) CSR finalize: count -> scan -> row_ptr -> col

__global__ __launch_bounds__(256) void bucket_csr_kernel(
    const int* __restrict__ offs, const unsigned char* __restrict__ dsub8,
    const int* __restrict__ esrc, int* __restrict__ row_ptr,
    int* __restrict__ col, int G1, int n) {
    __shared__ unsigned int cnt[256];
    __shared__ int rp[256];
    int t = threadIdx.x;
    int b = blockIdx.x;
    cnt[t] = 0;
    __syncthreads();
    int bs = offs[b * G1];
    int be = offs[(b + 1) * G1];
    for (int i = bs + t; i < be; i += 256) {
        atomicAdd(&cnt[dsub8[i]], 1u);
    }
    __syncthreads();
    int v = (int)cnt[t];
    rp[t] = v;
    __syncthreads();
    for (int off = 1; off < 256; off <<= 1) {
        int u = (t >= off) ? rp[t - off] : 0;
        __syncthreads();
        rp[t] += u;
        __syncthreads();
    }
    int excl = rp[t] - v;
    int node = b * 256 + t;
    if (node <= n) row_ptr[node] = bs + excl;  // node==n lands here too (E)
    __syncthreads();
    cnt[t] = (unsigned)excl;  // running cursors
    __syncthreads();
    for (int i = bs + t; i < be; i += 256) {
        int sub = dsub8[i];
        unsigned r = atomicAdd(&cnt[sub], 1u);
        col[bs + (int)r] = esrc[i];
    }
}

// fp8 h byte position for channel c: 2-head interleaved pairs, 1-head flat
template <int OUT, int HEADS>
__device__ __forceinline__ int hpos8(int c) {
    return (HEADS == 2) ? (2 * (c & 63) + (c >> 6)) : c;
}

// ---------------- MFMA transform (K=128): h(fp8)=xb(bf16)@W, as/ad ---------

template <int OUT, int HEADS>
__global__ __launch_bounds__(256) void transform_mfma_kernel(
    const unsigned short* __restrict__ xb, const unsigned short* __restrict__ Wf,
    const float* __restrict__ a_src, const float* __restrict__ a_dst,
    unsigned char* __restrict__ h, float* __restrict__ as_o, float* __restrict__ ad_o,
    int n) {
    constexpr int T = OUT / 16, S = 4;  // K = 128
    const int w = threadIdx.x >> 6, lane = threadIdx.x & 63;
    const int node0 = (blockIdx.x * 4 + w) * 16;
    if (node0 >= n) return;
    const int quad = lane >> 4, col = lane & 15;

    const int arow = node0 + col;
    const bool aok = arow < n;
    bf16x8 a[S];
    const unsigned short* xrow = xb + (size_t)arow * 128 + quad * 8;
#pragma unroll
    for (int s = 0; s < S; s++) {
        bf16x8 z = {0, 0, 0, 0, 0, 0, 0, 0};
        a[s] = aok ? *(const bf16x8*)(xrow + s * 32) : z;
    }

    f32x4 acc[T];
#pragma unroll
    for (int t = 0; t < T; t++) acc[t] = (f32x4){0.f, 0.f, 0.f, 0.f};

#pragma unroll
    for (int s = 0; s < S; s++) {
#pragma unroll
        for (int t = 0; t < T; t++) {
            bf16x8 b = *(const bf16x8*)(Wf + ((size_t)(t * S + s) * 64 + lane) * 8);
            acc[t] = __builtin_amdgcn_mfma_f32_16x16x32_bf16(a[s], b, acc[t], 0, 0, 0);
        }
    }

#pragma unroll
    for (int t = 0; t < T; t++) {
        int pos = hpos8<OUT, HEADS>(t * 16 + col);
#pragma unroll
        for (int r = 0; r < 4; r++) {
            int m = node0 + quad * 4 + r;
            if (m < n) h[(size_t)m * OUT + pos] = f2fp8(acc[t][r]);
        }
    }

#pragma unroll
    for (int r = 0; r < 4; r++) {
        float s0 = 0.f, s1 = 0.f, d0 = 0.f, d1 = 0.f;
#pragma unroll
        for (int t = 0; t < T; t++) {
            float av = a_src[t * 16 + col];
            float dv = a_dst[t * 16 + col];
            float v = acc[t][r];
            if (HEADS == 2 && t >= T / 2) { s1 += v * av; d1 += v * dv; }
            else                          { s0 += v * av; d0 += v * dv; }
        }
        for (int off = 8; off; off >>= 1) {
            s0 += __shfl_xor(s0, off, 64);
            d0 += __shfl_xor(d0, off, 64);
            if (HEADS == 2) {
                s1 += __shfl_xor(s1, off, 64);
                d1 += __shfl_xor(d1, off, 64);
            }
        }
        int m = node0 + quad * 4 + r;
        if (m < n) {
            if (HEADS == 2) {
                if (col == 0)      { as_o[m * 2] = s0;     ad_o[m * 2] = d0; }
                else if (col == 1) { as_o[m * 2 + 1] = s1; ad_o[m * 2 + 1] = d1; }
            } else {
                if (col == 0) { as_o[m] = s0; ad_o[m] = d0; }
            }
        }
    }
}

// ------- GAT aggregation, 2 heads (fp8 h): TWO nodes per wave --------------

template <int ACT>  // 1 = elu
__global__ __launch_bounds__(256) void agg2_kernel(
    const int* __restrict__ row_ptr, const int* __restrict__ col,
    const unsigned char* __restrict__ h, const float2* __restrict__ as2,
    const float2* __restrict__ ad2, const float* __restrict__ bias,
    unsigned short* __restrict__ out, int n) {
    __shared__ float w0l[4][2][32], w1l[4][2][32];
    __shared__ unsigned sofl[4][2][32];
    const int w = threadIdx.x >> 6;
    const int lane = threadIdx.x & 63;
    const int half = lane >> 5, l = lane & 31;
    const int node = blockIdx.x * 8 + w * 2 + half;
    const bool active = node < n;

    int beg = 0, deg = 0;
    float2 adv = make_float2(0.f, 0.f);
    float den0 = 0.f, den1 = 0.f;
    float a0 = 0.f, a1 = 0.f, a2 = 0.f, a3 = 0.f;
    if (active) {
        beg = row_ptr[node];
        deg = row_ptr[node + 1] - beg;
        adv = ad2[node];
        float2 avs = as2[node];
        float w0s = __expf(LRELU(avs.x + adv.x));
        float w1s = __expf(LRELU(avs.y + adv.y));
        unsigned us = *(const unsigned*)(h + ((size_t)node << 7) + 4 * l);
        f32x2 p0 = fp8pair(us & 0xffffu);
        f32x2 p1 = fp8pair(us >> 16);
        a0 = w0s * p0.x; a1 = w1s * p0.y;
        a2 = w0s * p1.x; a3 = w1s * p1.y;
        den0 = w0s; den1 = w1s;
    }
    int dmax = deg;
    for (int off = 32; off; off >>= 1) dmax = max(dmax, __shfl_xor(dmax, off, 64));

    for (int base = 0; base < dmax; base += 32) {
        int cnt = deg - base;
        cnt = cnt < 0 ? 0 : (cnt > 32 ? 32 : cnt);
        float w0 = 0.f, w1 = 0.f;
        unsigned so = 0;
        if (l < cnt) {
            int s = col[beg + base + l];
            float2 av = as2[s];
            w0 = __expf(LRELU(av.x + adv.x));
            w1 = __expf(LRELU(av.y + adv.y));
            so = (unsigned)s << 7;
        }
        float t0 = w0, t1 = w1;
        for (int off = 16; off; off >>= 1) {
            t0 += __shfl_xor(t0, off, 64);
            t1 += __shfl_xor(t1, off, 64);
        }
        den0 += t0; den1 += t1;
        w0l[w][half][l] = w0;
        w1l[w][half][l] = w1;
        sofl[w][half][l] = so;

        int jmax = dmax - base;
        jmax = jmax > 32 ? 32 : jmax;
        for (int j = 0; j < jmax; j += 8) {
            unsigned u[8];
#pragma unroll
            for (int k = 0; k < 8; k++) {
                unsigned so_k = sofl[w][half][j + k];
                u[k] = *(const unsigned*)(h + so_k + 4 * l);
            }
            float W0[8], W1[8];
#pragma unroll
            for (int k = 0; k < 8; k++) {
                W0[k] = w0l[w][half][j + k];
                W1[k] = w1l[w][half][j + k];
            }
#pragma unroll
            for (int k = 0; k < 8; k++) {
                f32x2 p0 = fp8pair(u[k] & 0xffffu);
                f32x2 p1 = fp8pair(u[k] >> 16);
                a0 += W0[k] * p0.x; a1 += W1[k] * p0.y;
                a2 += W0[k] * p1.x; a3 += W1[k] * p1.y;
            }
        }
    }

    if (active) {
        float2 bA = *(const float2*)(bias + 2 * l);
        float2 bB = *(const float2*)(bias + 64 + 2 * l);
        float r0 = 1.f / (den0 + 1e-16f), r1 = 1.f / (den1 + 1e-16f);
        float o0 = a0 * r0 + bA.x;
        float o1 = a1 * r1 + bB.x;
        float o2 = a2 * r0 + bA.y;
        float o3 = a3 * r1 + bB.y;
        if (ACT) {
            o0 = o0 > 0.f ? o0 : expm1f(o0);
            o1 = o1 > 0.f ? o1 : expm1f(o1);
            o2 = o2 > 0.f ? o2 : expm1f(o2);
            o3 = o3 > 0.f ? o3 : expm1f(o3);
        }
        unsigned h0 = (unsigned)f2bf(o0) | ((unsigned)f2bf(o2) << 16);
        unsigned h1 = (unsigned)f2bf(o1) | ((unsigned)f2bf(o3) << 16);
        *(unsigned*)(out + (size_t)node * 128 + 2 * l) = h0;
        *(unsigned*)(out + (size_t)node * 128 + 64 + 2 * l) = h1;
    }
}

// ------- GAT aggregation, 1 head (fp8 h, layer 2): two nodes per wave ------

__global__ __launch_bounds__(256) void agg1_kernel(
    const int* __restrict__ row_ptr, const int* __restrict__ col,
    const unsigned char* __restrict__ h, const float* __restrict__ as1,
    const float* __restrict__ ad1, const float* __restrict__ bias,
    unsigned short* __restrict__ out, int n) {
    __shared__ float wl[4][2][32];
    __shared__ unsigned sofl[4][2][32];
    const int w = threadIdx.x >> 6;
    const int lane = threadIdx.x & 63;
    const int half = lane >> 5, l = lane & 31;
    const int node = blockIdx.x * 8 + w * 2 + half;
    const bool active = node < n;

    int beg = 0, deg = 0;
    float adv = 0.f, den = 0.f, a0 = 0.f, a2 = 0.f;
    if (active) {
        beg = row_ptr[node];
        deg = row_ptr[node + 1] - beg;
        adv = ad1[node];
        float ws = __expf(LRELU(as1[node] + adv));
        unsigned us = *(const unsigned short*)(h + ((size_t)node << 6) + 2 * l);
        f32x2 p = fp8pair(us);
        a0 = ws * p.x;
        a2 = ws * p.y;
        den = ws;
    }
    int dmax = deg;
    for (int off = 32; off; off >>= 1) dmax = max(dmax, __shfl_xor(dmax, off, 64));

    for (int base = 0; base < dmax; base += 32) {
        int cnt = deg - base;
        cnt = cnt < 0 ? 0 : (cnt > 32 ? 32 : cnt);
        float w0 = 0.f;
        unsigned so = 0;
        if (l < cnt) {
            int s = col[beg + base + l];
            w0 = __expf(LRELU(as1[s] + adv));
            so = (unsigned)s << 6;
        }
        float t = w0;
        for (int off = 16; off; off >>= 1) t += __shfl_xor(t, off, 64);
        den += t;
        wl[w][half][l] = w0;
        sofl[w][half][l] = so;

        int jmax = dmax - base;
        jmax = jmax > 32 ? 32 : jmax;
        for (int j = 0; j < jmax; j += 8) {
            unsigned u[8];
#pragma unroll
            for (int k = 0; k < 8; k++) {
                unsigned so_k = sofl[w][half][j + k];
                u[k] = *(const unsigned short*)(h + so_k + 2 * l);
            }
            float W0[8];
#pragma unroll
            for (int k = 0; k < 8; k++) W0[k] = wl[w][half][j + k];
#pragma unroll
            for (int k = 0; k < 8; k++) {
                f32x2 p = fp8pair(u[k]);
                a0 += W0[k] * p.x;
                a2 += W0[k] * p.y;
            }
        }
    }

    if (active) {
        float2 bA = *(const float2*)(bias + 2 * l);
        float r = 1.f / (den + 1e-16f);
        float o0 = a0 * r + bA.x;
        float o2 = a2 * r + bA.y;
        unsigned hv = (unsigned)f2bf(o0) | ((unsigned)f2bf(o2) << 16);
        *(unsigned*)(out + (size_t)node * 64 + 2 * l) = hv;
    }
}

// ------- MLP head (pool fused): 512 threads/block, one block per graph -----

__global__ __launch_bounds__(512) void mlp_kernel(
    const unsigned short* __restrict__ xbuf, const int* __restrict__ gstart,
    const float* __restrict__ obs,
    const float* __restrict__ Ws1, const float* __restrict__ bs1,
    const float* __restrict__ ln_g, const float* __restrict__ ln_b,
    const float* __restrict__ Ws2, const float* __restrict__ bs2,
    const float* __restrict__ Wa, const float* __restrict__ ba,
    const float* __restrict__ Wc, const float* __restrict__ bc,
    float* __restrict__ out_logits, float* __restrict__ out_value) {
    int b = blockIdx.x;
    int t = threadIdx.x;
    __shared__ float comb[192];
    __shared__ float red[512];
    __shared__ float red2[8][64];
    __shared__ float hs[256];

    const int gs = gstart[b];
    const int ge = gstart[b + 1];

    // ---- pool: 64 rowgroups (8/wave) x 8 chunks of ushort8 ----
    {
        const int w = t >> 6, lane = t & 63;
        const int rg = w * 8 + (lane >> 3);
        const int sub = lane & 7;
        float acc[8];
#pragma unroll
        for (int j = 0; j < 8; j++) acc[j] = 0.f;
        for (int i = gs + rg; i < ge; i += 64) {
            u16x8 v = *(const u16x8*)(xbuf + (size_t)i * 64 + sub * 8);
#pragma unroll
            for (int j = 0; j < 8; j++) acc[j] += bf2f(v[j]);
        }
#pragma unroll
        for (int off = 8; off <= 32; off <<= 1) {
#pragma unroll
            for (int j = 0; j < 8; j++) acc[j] += __shfl_xor(acc[j], off, 64);
        }
        if (lane < 8) {
#pragma unroll
            for (int j = 0; j < 8; j++) red2[w][lane * 8 + j] = acc[j];
        }
    }
    __syncthreads();
    {
        float cdiv = fmaxf((float)(ge - gs), 1.f);
        if (t < 64) {
            float s = 0.f;
#pragma unroll
            for (int w = 0; w < 8; w++) s += red2[w][t];
            comb[t] = s / cdiv;
        } else if (t < 192) {
            comb[t] = obs[b * 128 + (t - 64)];
        }
    }
    __syncthreads();

    const int t256 = t & 255;
    const int khalf = t >> 8;

    // ---- fc1: k split 2x96 ----
    {
        float accA = 0.f, accB = 0.f;
        int k0 = khalf * 96;
#pragma unroll 4
        for (int k = k0; k < k0 + 96; k += 2) {
            accA += comb[k] * Ws1[k * 256 + t256];
            accB += comb[k + 1] * Ws1[(k + 1) * 256 + t256];
        }
        red[t] = accA + accB;
    }
    __syncthreads();
    float acc = 0.f;
    if (t < 256) acc = bs1[t] + red[t] + red[t + 256];
    __syncthreads();

    // ---- LayerNorm over 256 ----
    red[t] = (t < 256) ? acc : 0.f;
    __syncthreads();
    for (int off = 128; off; off >>= 1) {
        if (t < off) red[t] += red[t + off];
        __syncthreads();
    }
    float mu = red[0] / 256.f;
    __syncthreads();
    float d = acc - mu;
    red[t] = (t < 256) ? d * d : 0.f;
    __syncthreads();
    for (int off = 128; off; off >>= 1) {
        if (t < off) red[t] += red[t + off];
        __syncthreads();
    }
    float var = red[0] / 256.f;
    if (t < 256) {
        float hn = d * rsqrtf(var + 1e-5f) * ln_g[t] + ln_b[t];
        hs[t] = hn > 0.f ? hn : 0.f;
    }
    __syncthreads();

    // ---- fc2: k split 2x128 ----
    {
        float a2A = 0.f, a2B = 0.f;
        int k0 = khalf * 128;
#pragma unroll 4
        for (int k = k0; k < k0 + 128; k += 2) {
            a2A += hs[k] * Ws2[k * 256 + t256];
            a2B += hs[k + 1] * Ws2[(k + 1) * 256 + t256];
        }
        red[t] = a2A + a2B;
    }
    __syncthreads();
    float acc2 = 0.f;
    if (t < 256) {
        acc2 = bs2[t] + red[t] + red[t + 256];
        acc2 = acc2 > 0.f ? acc2 : 0.f;
    }
    __syncthreads();
    if (t < 256) hs[t] = acc2;
    __syncthreads();

    // ---- logits: 16 outs x 32 k-chunks of 8 + LDS tree ----
    {
        int o = t & 15, ck = t >> 4;
        float p = 0.f;
#pragma unroll
        for (int k = 0; k < 8; k++)
            p += hs[ck * 8 + k] * Wa[(ck * 8 + k) * 16 + o];
        red[t] = p;
    }
    __syncthreads();
    for (int off = 16; off >= 1; off >>= 1) {
        if ((t >> 4) < off) red[t] += red[t + off * 16];
        __syncthreads();
    }
    if (t < 16) out_logits[b * 16 + t] = red[t] + ba[t];
    __syncthreads();

    // ---- value: full-width dot + tree over 512 ----
    red[t] = (t < 256) ? hs[t] * Wc[t] : 0.f;
    __syncthreads();
    for (int off = 256; off; off >>= 1) {
        if (t < off) red[t] += red[t + off];
        __syncthreads();
    }
    if (t == 0) out_value[b] = red[0] + bc[0];
}

// ---------------------------------------------------------------------------

extern "C" void kernel_launch(void* const* d_in, const int* in_sizes, int n_in,
                              void* d_out, int out_size, void* d_ws, size_t ws_size,
                              hipStream_t stream) {
    const float* obs    = (const float*)d_in[0];
    const float* nf     = (const float*)d_in[1];
    const int*   ei     = (const int*)d_in[2];
    const int*   batch  = (const int*)d_in[3];
    const float* W0     = (const float*)d_in[4];
    const float* a_src0 = (const float*)d_in[5];
    const float* a_dst0 = (const float*)d_in[6];
    const float* b0     = (const float*)d_in[7];
    const float* W1     = (const float*)d_in[8];
    const float* a_src1 = (const float*)d_in[9];
    const float* a_dst1 = (const float*)d_in[10];
    const float* b1     = (const float*)d_in[11];
    const float* W2     = (const float*)d_in[12];
    const float* a_src2 = (const float*)d_in[13];
    const float* a_dst2 = (const float*)d_in[14];
    const float* b2     = (const float*)d_in[15];
    const float* Ws1    = (const float*)d_in[16];
    const float* bs1    = (const float*)d_in[17];
    const float* ln_g   = (const float*)d_in[18];
    const float* ln_b   = (const float*)d_in[19];
    const float* Ws2    = (const float*)d_in[20];
    const float* bs2    = (const float*)d_in[21];
    const float* Wa     = (const float*)d_in[22];
    const float* ba     = (const float*)d_in[23];
    const float* Wc     = (const float*)d_in[24];
    const float* bc     = (const float*)d_in[25];

    const int N = in_sizes[3];
    const int E = in_sizes[2] / 2;
    const int B = in_sizes[0] / 128;
    const int* src = ei;
    const int* dstp = ei + E;

    // workspace carve (256B aligned)
    char* p = (char*)d_ws;
    auto alloc = [&](size_t bytes) -> void* {
        void* r = (void*)p;
        p += (bytes + 255) & ~(size_t)255;
        return r;
    };
    const int G1 = (E + 2047) / 2048;       // edge chunks (2048/block)
    const int NB = (N + 255) >> 8;          // dst buckets of 256 (n <= 65536)
    const int L  = NB * G1;                 // histT length
    int*   row_ptr   = (int*)alloc((size_t)(N + 1) * 4);
    int*   col       = (int*)alloc((size_t)E * 4);
    int*   esrc      = (int*)alloc((size_t)E * 4);           // bucketed src
    unsigned char* dsub8 = (unsigned char*)alloc((size_t)E); // bucketed dst&255
    int*   histT     = (int*)alloc((size_t)L * 4);           // [b][g]
    int*   offs      = (int*)alloc((size_t)(L + 1) * 4);
    unsigned char* hbuf = (unsigned char*)alloc((size_t)N * 128);       // fp8
    unsigned short* xb = (unsigned short*)alloc((size_t)N * 128 * 2);   // bf16
    unsigned short* xbuf = (unsigned short*)alloc((size_t)N * 64 * 2);  // bf16
    float* as_       = (float*)alloc((size_t)N * 2 * 4);
    float* ad_       = (float*)alloc((size_t)N * 2 * 4);
    unsigned short* Wf1 = (unsigned short*)alloc((size_t)8 * 4 * 64 * 8 * 2);
    unsigned short* Wf2 = (unsigned short*)alloc((size_t)4 * 4 * 64 * 8 * 2);
    int* gstart      = (int*)alloc((size_t)(B + 1) * 4);
    // scratch (blockSums) aliases xb region: scanA completes (stream-ordered)
    // before xb's first write (agg2, layer 0).
    int* blockSums = (int*)xb;   // up to 256 entries

    float* out_logits = (float*)d_out;
    float* out_value  = out_logits + (size_t)B * 16;

    // ---- P1: hist || transform0 || W pack || gstart (1 dispatch) ----
    int t0_blocks = (N + 15) / 16;
    int wp_blocks = (8 * 4 * 64 + 4 * 4 * 64 + 255) / 256;
    int gb_blocks = (N + 255) / 256;
    hist_t0_kernel<<<G1 + t0_blocks + wp_blocks + gb_blocks, 256, 0, stream>>>(
        dstp, histT, E, G1, NB, N, G1, t0_blocks, wp_blocks,
        nf, W0, a_src0, a_dst0, hbuf, as_, ad_,
        W1, W2, Wf1, Wf2, batch, gstart, B);

    // ---- scanA over histT -> offs (2 small dispatches) ----
    int nbA = (L + 511) / 512;
    scan2_block_kernel<<<nbA, 256, 0, stream>>>(histT, offs, blockSums, L);
    scan2_finalize_kernel<<<(L + 1 + 511) / 512, 256, 0, stream>>>(offs, blockSums, L, nbA);

    // ---- P3 bucket partition (LDS-cached offs col) + P4 finalize ----
    bucket_scatter_kernel<<<G1, 256, 0, stream>>>(src, dstp, offs, esrc, dsub8, E, G1, NB);
    bucket_csr_kernel<<<NB, 256, 0, stream>>>(offs, dsub8, esrc, row_ptr, col, G1, N);

    // ---- GAT layer 0 aggregation (transform fused into P1) ----
    agg2_kernel<1><<<(N + 7) / 8, 256, 0, stream>>>(
        row_ptr, col, hbuf, (const float2*)as_, (const float2*)ad_, b0, xb, N);

    // ---- GAT layer 1: in=128 -> concat, elu (MFMA transform) ----
    transform_mfma_kernel<128, 2><<<(N + 63) / 64, 256, 0, stream>>>(
        xb, Wf1, a_src1, a_dst1, hbuf, as_, ad_, N);
    agg2_kernel<1><<<(N + 7) / 8, 256, 0, stream>>>(
        row_ptr, col, hbuf, (const float2*)as_, (const float2*)ad_, b1, xb, N);

    // ---- GAT layer 2: in=128 -> heads=1, out=64 (MFMA transform) ----
    transform_mfma_kernel<64, 1><<<(N + 63) / 64, 256, 0, stream>>>(
        xb, Wf2, a_src2, a_dst2, hbuf, as_, ad_, N);
    agg1_kernel<<<(N + 7) / 8, 256, 0, stream>>>(
        row_ptr, col, hbuf, as_, ad_, b2, xbuf, N);

    // ---- MLP head with fused mean-pool (1 dispatch, no atomics) ----
    mlp_kernel<<<B, 512, 0, stream>>>(xbuf, gstart, obs, Ws1, bs1, ln_g, ln_b,
                                      Ws2, bs2, Wa, ba, Wc, bc,
                                      out_logits, out_value);
}

// Round 9
// 259.541 us; speedup vs baseline: 1.1118x; 1.0100x over previous
//
#include <hip/hip_runtime.h>
#include <math.h>

// ---------------------------------------------------------------------------
// GATPolicy: 3x GATConv (with self loops) + mean-pool + MLP head.
// CSR-by-dst with ZERO global atomics (r1: device-scope atomicAdd bypasses
// the non-coherent XCD L2s; 56us). r8 structure (262us) + NEW r9 fusion:
// the K=128 MFMA transform of layer l+1 is fused into the EPILOGUE of agg
// layer l (transform is row-wise on the agg's own 16 output rows): agg
// results go to LDS xs[16][136] (bf16; 17x16B row stride = aligned b128,
// bank-uniform), syncthreads, then the block's 8 waves each run one 16-col
// MFMA tile, write fp8 h + LDS-reduced as/ad. Removes 2 dispatches + the
// 25.6MB xb round-trip; h/as/ad ping-pong A<->B buffers (no intra-dispatch
// read/write overlap). Numerics identical (same bf16 round-trip, same fp8).
//   P1    hist | transform0 | W pack | gstart     (1 dispatch)
//   scanA histT -> offs (2 small dispatches)
//   P3    partition (LDS ranks, LDS-cached offs col) -> esrc/dsub8
//   P4    per-bucket: count -> scan -> row_ptr -> col
//   agg2t<128,2> layer0 agg + transform1          (hA,as0 -> hB,as1)
//   agg2t<64,1>  layer1 agg + transform2          (hB,as1 -> hA,as2)
//   agg1  layer2 agg -> xbuf
//   mlp   pool-fused head (gstart, 512 thr)
// AGG core (r4/r5): 2 nodes per wave; lane l gathers dword = ch{2l,2l+1}x2
// heads (fp8-interleaved); 32-edge chunks stage {w0,w1,rowoff} to wave LDS,
// consume as uniform-per-half broadcasts, 8 loads in flight.
// (r13: never chain blocks across XCDs. r6/r7: don't fuse the offs scan.)
// ---------------------------------------------------------------------------

#define LRELU(x) ((x) > 0.f ? (x) : 0.2f * (x))

typedef short bf16x8 __attribute__((ext_vector_type(8)));
typedef unsigned short u16x8 __attribute__((ext_vector_type(8)));
typedef float f32x4 __attribute__((ext_vector_type(4)));
typedef float f32x2 __attribute__((ext_vector_type(2)));

__device__ __forceinline__ unsigned short f2bf(float f) {
    unsigned int u = __float_as_uint(f);
    u = (u + 0x7fffu + ((u >> 16) & 1u)) >> 16;  // RNE
    return (unsigned short)u;
}
__device__ __forceinline__ float bf2f(unsigned short u) {
    return __uint_as_float((unsigned int)u << 16);
}
__device__ __forceinline__ unsigned char f2fp8(float f) {
    return (unsigned char)(__builtin_amdgcn_cvt_pk_fp8_f32(f, f, 0, false) & 0xff);
}
__device__ __forceinline__ f32x2 fp8pair(unsigned int u) {
    return __builtin_amdgcn_cvt_pk_f32_fp8(u, false);  // bytes 0,1
}

// fp8 h byte position for channel c: 2-head interleaved pairs, 1-head flat
template <int OUT, int HEADS>
__device__ __forceinline__ int hpos8(int c) {
    return (HEADS == 2) ? (2 * (c & 63) + (c >> 6)) : c;
}

// -- P1: bucket hist (2048-edge chunks) || transform0 || W pack || gstart ---

__global__ __launch_bounds__(256) void hist_t0_kernel(
    const int* __restrict__ dst, int* __restrict__ histT,
    int e, int G1, int NB, int n, int hist_blocks, int t0_blocks, int wp_blocks,
    const float* __restrict__ x, const float* __restrict__ W,
    const float* __restrict__ a_src, const float* __restrict__ a_dst,
    unsigned char* __restrict__ h, float* __restrict__ as_o,
    float* __restrict__ ad_o,
    const float* __restrict__ W1, const float* __restrict__ W2,
    unsigned short* __restrict__ Wf1, unsigned short* __restrict__ Wf2,
    const int* __restrict__ batch, int* __restrict__ gstart, int nGraphs) {
    __shared__ unsigned int hist[256];
    __shared__ float xs[2][8][8];
    const int t = threadIdx.x;
    if ((int)blockIdx.x < hist_blocks) {
        hist[t] = 0;
        __syncthreads();
        int base = blockIdx.x * 2048 + t * 8;
        int d[8];
        if (base + 8 <= e) {
            int4 x0 = *(const int4*)(dst + base);
            int4 x1 = *(const int4*)(dst + base + 4);
            d[0] = x0.x; d[1] = x0.y; d[2] = x0.z; d[3] = x0.w;
            d[4] = x1.x; d[5] = x1.y; d[6] = x1.z; d[7] = x1.w;
        } else {
#pragma unroll
            for (int j = 0; j < 8; j++) {
                int ij = base + j;
                d[j] = (ij < e) ? dst[ij] : -1;
            }
        }
#pragma unroll
        for (int j = 0; j < 8; j++) {
            if (d[j] >= 0) atomicAdd(&hist[d[j] >> 8], 1u);
        }
        __syncthreads();
        if (t < NB) histT[t * G1 + blockIdx.x] = (int)hist[t];
        return;
    }
    if ((int)blockIdx.x < hist_blocks + t0_blocks) {
        // ---- transform0 path: h(fp8)=x@W0, as/ad. 16 nodes/block ----
        const int bid2 = blockIdx.x - hist_blocks;
        const int tid = t & 127;
        const int half = t >> 7;
        const int node0 = bid2 * 16 + half * 8;

        for (int idx = tid; idx < 64; idx += 128) {
            int ni = idx >> 3, k = idx & 7;
            int ng = node0 + ni;
            xs[half][ni][k] = (ng < n) ? x[(size_t)ng * 8 + k] : 0.f;
        }
        __syncthreads();

        float acc[8];
#pragma unroll
        for (int i = 0; i < 8; i++) acc[i] = 0.f;
#pragma unroll
        for (int k = 0; k < 8; k++) {
            float wk = W[k * 128 + tid];
#pragma unroll
            for (int i = 0; i < 8; i++) acc[i] += xs[half][i][k] * wk;
        }

        const int lane = tid & 63;
        const int head = tid >> 6;
        const int pos = 2 * lane + head;  // 2-head interleaved fp8 byte pos
        const float av = a_src[tid];
        const float dv = a_dst[tid];
#pragma unroll
        for (int i = 0; i < 8; i++) {
            int ng = node0 + i;
            if (ng >= n) break;
            h[(size_t)ng * 128 + pos] = f2fp8(acc[i]);
            float ps = acc[i] * av, pd = acc[i] * dv;
            for (int off = 32; off; off >>= 1) {
                ps += __shfl_xor(ps, off, 64);
                pd += __shfl_xor(pd, off, 64);
            }
            if (lane == 0) {
                as_o[ng * 2 + head] = ps;
                ad_o[ng * 2 + head] = pd;
            }
        }
        return;
    }
    if ((int)blockIdx.x < hist_blocks + t0_blocks + wp_blocks) {
        // ---- W pack path ----
        const int n1 = 8 * 4 * 64;   // W1 fragment rows (OUT=128)
        const int n2 = 4 * 4 * 64;   // W2 fragment rows (OUT=64)
        int gid = (blockIdx.x - hist_blocks - t0_blocks) * 256 + t;
        if (gid < n1) {
            int idx = gid;
            int lane = idx & 63, ts = idx >> 6;
            int s = ts & 3, tt = ts >> 2;
            int quad = lane >> 4, cn = lane & 15;
#pragma unroll
            for (int j = 0; j < 8; j++)
                Wf1[idx * 8 + j] = f2bf(W1[(s * 32 + quad * 8 + j) * 128 + tt * 16 + cn]);
        } else if (gid < n1 + n2) {
            int idx = gid - n1;
            int lane = idx & 63, ts = idx >> 6;
            int s = ts & 3, tt = ts >> 2;
            int quad = lane >> 4, cn = lane & 15;
#pragma unroll
            for (int j = 0; j < 8; j++)
                Wf2[idx * 8 + j] = f2bf(W2[(s * 32 + quad * 8 + j) * 64 + tt * 16 + cn]);
        }
        return;
    }
    // ---- gstart path: graph boundaries of sorted batch ----
    int gid = (blockIdx.x - hist_blocks - t0_blocks - wp_blocks) * 256 + t;
    if (gid < n) {
        int bi = batch[gid];
        if (gid == 0) {
            for (int g = 0; g <= bi; g++) gstart[g] = 0;
        } else {
            int bp = batch[gid - 1];
            if (bi != bp)
                for (int g = bp + 1; g <= bi; g++) gstart[g] = gid;
        }
        if (gid == n - 1) {
            for (int g = bi + 1; g <= nGraphs; g++) gstart[g] = n;
        }
    }
}

// ---------------- generalized scan: 512 elements per block -----------------

__global__ __launch_bounds__(256) void scan2_block_kernel(
    const int* __restrict__ in, int* __restrict__ out,
    int* __restrict__ blockSums, int len) {
    __shared__ int lds[256];
    int t = threadIdx.x;
    int i0 = blockIdx.x * 512 + 2 * t;
    int v0 = (i0 < len) ? in[i0] : 0;
    int v1 = (i0 + 1 < len) ? in[i0 + 1] : 0;
    int s = v0 + v1;
    lds[t] = s;
    __syncthreads();
    for (int off = 1; off < 256; off <<= 1) {
        int u = (t >= off) ? lds[t - off] : 0;
        __syncthreads();
        lds[t] += u;
        __syncthreads();
    }
    int base = lds[t] - s;  // block-local exclusive for element i0
    if (i0 < len) out[i0] = base;
    if (i0 + 1 < len) out[i0 + 1] = base + v0;
    if (t == 255) blockSums[blockIdx.x] = lds[255];
}

// Every block redundantly scans blockSums (nb <= 256) and applies its base.
__global__ __launch_bounds__(256) void scan2_finalize_kernel(
    int* __restrict__ out, const int* __restrict__ blockSums, int len, int nb) {
    __shared__ int lds[256];
    int t = threadIdx.x;
    int v = (t < nb) ? blockSums[t] : 0;
    lds[t] = v;
    __syncthreads();
    for (int off = 1; off < 256; off <<= 1) {
        int u = (t >= off) ? lds[t - off] : 0;
        __syncthreads();
        lds[t] += u;
        __syncthreads();
    }
    const int bid = blockIdx.x;
    const int base = (bid > 0) ? lds[bid - 1] : 0;
    const int total = lds[nb - 1];
    int i0 = bid * 512 + 2 * t;
#pragma unroll
    for (int q = 0; q < 2; q++) {
        int i = i0 + q;
        if (i < len) out[i] += base;
        else if (i == len) out[len] = total;
    }
}

// -- P3: bucket partition (LDS ranks; offs column cached in LDS) ------------

__global__ __launch_bounds__(256) void bucket_scatter_kernel(
    const int* __restrict__ src, const int* __restrict__ dst,
    const int* __restrict__ offs, int* __restrict__ esrc,
    unsigned char* __restrict__ dsub8, int e, int G1, int NB) {
    __shared__ unsigned int hist[256];
    __shared__ int baseL[256];
    const int t = threadIdx.x;
    hist[t] = 0;
    if (t < NB) baseL[t] = offs[t * G1 + blockIdx.x];
    __syncthreads();
    int base = blockIdx.x * 2048 + t * 8;
    int d[8], s[8];
    if (base + 8 <= e) {
        int4 d0 = *(const int4*)(dst + base);
        int4 d1 = *(const int4*)(dst + base + 4);
        int4 s0 = *(const int4*)(src + base);
        int4 s1 = *(const int4*)(src + base + 4);
        d[0] = d0.x; d[1] = d0.y; d[2] = d0.z; d[3] = d0.w;
        d[4] = d1.x; d[5] = d1.y; d[6] = d1.z; d[7] = d1.w;
        s[0] = s0.x; s[1] = s0.y; s[2] = s0.z; s[3] = s0.w;
        s[4] = s1.x; s[5] = s1.y; s[6] = s1.z; s[7] = s1.w;
    } else {
#pragma unroll
        for (int j = 0; j < 8; j++) {
            int ij = base + j;
            bool v = ij < e;
            d[j] = v ? dst[ij] : -1;
            s[j] = v ? src[ij] : 0;
        }
    }
    unsigned lr[8];
#pragma unroll
    for (int j = 0; j < 8; j++) {
        lr[j] = (d[j] >= 0) ? atomicAdd(&hist[d[j] >> 8], 1u) : 0u;
    }
#pragma unroll
    for (int j = 0; j < 8; j++) {
        if (d[j] >= 0) {
            int pos = baseL[d[j] >> 8] + (int)lr[j];
            esrc[pos] = s[j];
            dsub8[pos] = (unsigned char)(d[j] & 255);
        }
    }
}

// -- P4: per-bucket (256 nodes) CSR finalize: count -> scan -> row_ptr -> col

__global__ __launch_bounds__(256) void bucket_csr_kernel(
    const int* __restrict__ offs, const unsigned char* __restrict__ dsub8,
    const int* __restrict__ esrc, int* __restrict__ row_ptr,
    int* __restrict__ col, int G1, int n) {
    __shared__ unsigned int cnt[256];
    __shared__ int rp[256];
    int t = threadIdx.x;
    int b = blockIdx.x;
    cnt[t] = 0;
    __syncthreads();
    int bs = offs[b * G1];
    int be = offs[(b + 1) * G1];
    for (int i = bs + t; i < be; i += 256) {
        atomicAdd(&cnt[dsub8[i]], 1u);
    }
    __syncthreads();
    int v = (int)cnt[t];
    rp[t] = v;
    __syncthreads();
    for (int off = 1; off < 256; off <<= 1) {
        int u = (t >= off) ? rp[t - off] : 0;
        __syncthreads();
        rp[t] += u;
        __syncthreads();
    }
    int excl = rp[t] - v;
    int node = b * 256 + t;
    if (node <= n) row_ptr[node] = bs + excl;  // node==n lands here too (E)
    __syncthreads();
    cnt[t] = (unsigned)excl;  // running cursors
    __syncthreads();
    for (int i = bs + t; i < be; i += 256) {
        int sub = dsub8[i];
        unsigned r = atomicAdd(&cnt[sub], 1u);
        col[bs + (int)r] = esrc[i];
    }
}

// -- agg2t: 2-head agg (2 nodes/wave, 16 nodes/block) + FUSED next-layer ----
// MFMA transform. Agg outputs (bf16) -> LDS xs[16][136] -> per-wave 16-col
// tile transform -> fp8 hN + LDS-reduced asN/adN. OUT2 in {128,64}.

template <int OUT2, int HEADS2>
__global__ __launch_bounds__(512) void agg2t_kernel(
    const int* __restrict__ row_ptr, const int* __restrict__ col,
    const unsigned char* __restrict__ h, const float2* __restrict__ as2,
    const float2* __restrict__ ad2, const float* __restrict__ bias,
    const unsigned short* __restrict__ Wf, const float* __restrict__ aN_src,
    const float* __restrict__ aN_dst, unsigned char* __restrict__ hN,
    float* __restrict__ asN, float* __restrict__ adN, int n) {
    __shared__ float w0l[8][2][32], w1l[8][2][32];
    __shared__ unsigned sofl[8][2][32];
    __shared__ unsigned short xs[16][136];   // 272B row stride: b128-aligned
    __shared__ float asP[16][8], adP[16][8];
    const int w = threadIdx.x >> 6;
    const int lane = threadIdx.x & 63;
    const int half = lane >> 5, l = lane & 31;
    const int node0 = blockIdx.x * 16;
    const int mloc = w * 2 + half;
    const int node = node0 + mloc;
    const bool active = node < n;

    // ---------------- aggregation (2-head, fp8 h) ----------------
    int beg = 0, deg = 0;
    float2 adv = make_float2(0.f, 0.f);
    float den0 = 0.f, den1 = 0.f;
    float a0 = 0.f, a1 = 0.f, a2 = 0.f, a3 = 0.f;
    if (active) {
        beg = row_ptr[node];
        deg = row_ptr[node + 1] - beg;
        adv = ad2[node];
        float2 avs = as2[node];
        float w0s = __expf(LRELU(avs.x + adv.x));
        float w1s = __expf(LRELU(avs.y + adv.y));
        unsigned us = *(const unsigned*)(h + ((size_t)node << 7) + 4 * l);
        f32x2 p0 = fp8pair(us & 0xffffu);
        f32x2 p1 = fp8pair(us >> 16);
        a0 = w0s * p0.x; a1 = w1s * p0.y;
        a2 = w0s * p1.x; a3 = w1s * p1.y;
        den0 = w0s; den1 = w1s;
    }
    int dmax = deg;
    for (int off = 32; off; off >>= 1) dmax = max(dmax, __shfl_xor(dmax, off, 64));

    for (int base = 0; base < dmax; base += 32) {
        int cnt = deg - base;
        cnt = cnt < 0 ? 0 : (cnt > 32 ? 32 : cnt);
        float w0 = 0.f, w1 = 0.f;
        unsigned so = 0;
        if (l < cnt) {
            int s = col[beg + base + l];
            float2 av = as2[s];
            w0 = __expf(LRELU(av.x + adv.x));
            w1 = __expf(LRELU(av.y + adv.y));
            so = (unsigned)s << 7;
        }
        float t0 = w0, t1 = w1;
        for (int off = 16; off; off >>= 1) {
            t0 += __shfl_xor(t0, off, 64);
            t1 += __shfl_xor(t1, off, 64);
        }
        den0 += t0; den1 += t1;
        w0l[w][half][l] = w0;
        w1l[w][half][l] = w1;
        sofl[w][half][l] = so;

        int jmax = dmax - base;
        jmax = jmax > 32 ? 32 : jmax;
        for (int j = 0; j < jmax; j += 8) {
            unsigned u[8];
#pragma unroll
            for (int k = 0; k < 8; k++) {
                unsigned so_k = sofl[w][half][j + k];
                u[k] = *(const unsigned*)(h + so_k + 4 * l);
            }
            float W0[8], W1[8];
#pragma unroll
            for (int k = 0; k < 8; k++) {
                W0[k] = w0l[w][half][j + k];
                W1[k] = w1l[w][half][j + k];
            }
#pragma unroll
            for (int k = 0; k < 8; k++) {
                f32x2 p0 = fp8pair(u[k] & 0xffffu);
                f32x2 p1 = fp8pair(u[k] >> 16);
                a0 += W0[k] * p0.x; a1 += W1[k] * p0.y;
                a2 += W0[k] * p1.x; a3 += W1[k] * p1.y;
            }
        }
    }

    // epilogue -> LDS (bf16; same quantization as old global xb round-trip)
    if (active) {
        float2 bA = *(const float2*)(bias + 2 * l);
        float2 bB = *(const float2*)(bias + 64 + 2 * l);
        float r0 = 1.f / (den0 + 1e-16f), r1 = 1.f / (den1 + 1e-16f);
        float o0 = a0 * r0 + bA.x;  // ch2l   h0
        float o1 = a1 * r1 + bB.x;  // ch2l   h1
        float o2 = a2 * r0 + bA.y;  // ch2l+1 h0
        float o3 = a3 * r1 + bB.y;  // ch2l+1 h1
        o0 = o0 > 0.f ? o0 : expm1f(o0);
        o1 = o1 > 0.f ? o1 : expm1f(o1);
        o2 = o2 > 0.f ? o2 : expm1f(o2);
        o3 = o3 > 0.f ? o3 : expm1f(o3);
        *(unsigned*)&xs[mloc][2 * l] = (unsigned)f2bf(o0) | ((unsigned)f2bf(o2) << 16);
        *(unsigned*)&xs[mloc][64 + 2 * l] = (unsigned)f2bf(o1) | ((unsigned)f2bf(o3) << 16);
    } else {
        *(unsigned*)&xs[mloc][2 * l] = 0;
        *(unsigned*)&xs[mloc][64 + 2 * l] = 0;
    }
    __syncthreads();

    // ---------------- fused transform: hN = xs @ Wf ----------------
    constexpr int T2 = OUT2 / 16, S = 4;  // K = 128
    const int quad = lane >> 4, colc = lane & 15;
    if (w < T2) {
        bf16x8 a[S];
#pragma unroll
        for (int s = 0; s < S; s++)
            a[s] = *(const bf16x8*)&xs[colc][quad * 8 + s * 32];
        f32x4 acc = (f32x4){0.f, 0.f, 0.f, 0.f};
#pragma unroll
        for (int s = 0; s < S; s++) {
            bf16x8 b = *(const bf16x8*)(Wf + ((size_t)(w * S + s) * 64 + lane) * 8);
            acc = __builtin_amdgcn_mfma_f32_16x16x32_bf16(a[s], b, acc, 0, 0, 0);
        }
        const int pos = hpos8<OUT2, HEADS2>(w * 16 + colc);
#pragma unroll
        for (int r = 0; r < 4; r++) {
            int m = node0 + quad * 4 + r;
            if (m < n) hN[(size_t)m * OUT2 + pos] = f2fp8(acc[r]);
        }
        const float av = aN_src[w * 16 + colc];
        const float dv = aN_dst[w * 16 + colc];
#pragma unroll
        for (int r = 0; r < 4; r++) {
            float sp = acc[r] * av, dp = acc[r] * dv;
            for (int off = 8; off; off >>= 1) {
                sp += __shfl_xor(sp, off, 64);
                dp += __shfl_xor(dp, off, 64);
            }
            if (colc == 0) {
                asP[quad * 4 + r][w] = sp;
                adP[quad * 4 + r][w] = dp;
            }
        }
    }
    __syncthreads();
    const int tt = threadIdx.x;
    if (tt < 16 * HEADS2) {
        int m = tt & 15, head = tt >> 4;
        int node2 = node0 + m;
        if (node2 < n) {
            float s = 0.f, d = 0.f;
#pragma unroll
            for (int ww = 0; ww < 4; ww++) {
                s += asP[m][head * 4 + ww];
                d += adP[m][head * 4 + ww];
            }
            asN[node2 * HEADS2 + head] = s;
            adN[node2 * HEADS2 + head] = d;
        }
    }
}

// ------- GAT aggregation, 1 head (fp8 h, layer 2): two nodes per wave ------

__global__ __launch_bounds__(256) void agg1_kernel(
    const int* __restrict__ row_ptr, const int* __restrict__ col,
    const unsigned char* __restrict__ h, const float* __restrict__ as1,
    const float* __restrict__ ad1, const float* __restrict__ bias,
    unsigned short* __restrict__ out, int n) {
    __shared__ float wl[4][2][32];
    __shared__ unsigned sofl[4][2][32];
    const int w = threadIdx.x >> 6;
    const int lane = threadIdx.x & 63;
    const int half = lane >> 5, l = lane & 31;
    const int node = blockIdx.x * 8 + w * 2 + half;
    const bool active = node < n;

    int beg = 0, deg = 0;
    float adv = 0.f, den = 0.f, a0 = 0.f, a2 = 0.f;
    if (active) {
        beg = row_ptr[node];
        deg = row_ptr[node + 1] - beg;
        adv = ad1[node];
        float ws = __expf(LRELU(as1[node] + adv));
        unsigned us = *(const unsigned short*)(h + ((size_t)node << 6) + 2 * l);
        f32x2 p = fp8pair(us);
        a0 = ws * p.x;
        a2 = ws * p.y;
        den = ws;
    }
    int dmax = deg;
    for (int off = 32; off; off >>= 1) dmax = max(dmax, __shfl_xor(dmax, off, 64));

    for (int base = 0; base < dmax; base += 32) {
        int cnt = deg - base;
        cnt = cnt < 0 ? 0 : (cnt > 32 ? 32 : cnt);
        float w0 = 0.f;
        unsigned so = 0;
        if (l < cnt) {
            int s = col[beg + base + l];
            w0 = __expf(LRELU(as1[s] + adv));
            so = (unsigned)s << 6;
        }
        float t = w0;
        for (int off = 16; off; off >>= 1) t += __shfl_xor(t, off, 64);
        den += t;
        wl[w][half][l] = w0;
        sofl[w][half][l] = so;

        int jmax = dmax - base;
        jmax = jmax > 32 ? 32 : jmax;
        for (int j = 0; j < jmax; j += 8) {
            unsigned u[8];
#pragma unroll
            for (int k = 0; k < 8; k++) {
                unsigned so_k = sofl[w][half][j + k];
                u[k] = *(const unsigned short*)(h + so_k + 2 * l);
            }
            float W0[8];
#pragma unroll
            for (int k = 0; k < 8; k++) W0[k] = wl[w][half][j + k];
#pragma unroll
            for (int k = 0; k < 8; k++) {
                f32x2 p = fp8pair(u[k]);
                a0 += W0[k] * p.x;
                a2 += W0[k] * p.y;
            }
        }
    }

    if (active) {
        float2 bA = *(const float2*)(bias + 2 * l);
        float r = 1.f / (den + 1e-16f);
        float o0 = a0 * r + bA.x;
        float o2 = a2 * r + bA.y;
        unsigned hv = (unsigned)f2bf(o0) | ((unsigned)f2bf(o2) << 16);
        *(unsigned*)(out + (size_t)node * 64 + 2 * l) = hv;
    }
}

// ------- MLP head (pool fused): 512 threads/block, one block per graph -----

__global__ __launch_bounds__(512) void mlp_kernel(
    const unsigned short* __restrict__ xbuf, const int* __restrict__ gstart,
    const float* __restrict__ obs,
    const float* __restrict__ Ws1, const float* __restrict__ bs1,
    const float* __restrict__ ln_g, const float* __restrict__ ln_b,
    const float* __restrict__ Ws2, const float* __restrict__ bs2,
    const float* __restrict__ Wa, const float* __restrict__ ba,
    const float* __restrict__ Wc, const float* __restrict__ bc,
    float* __restrict__ out_logits, float* __restrict__ out_value) {
    int b = blockIdx.x;
    int t = threadIdx.x;
    __shared__ float comb[192];
    __shared__ float red[512];
    __shared__ float red2[8][64];
    __shared__ float hs[256];

    const int gs = gstart[b];
    const int ge = gstart[b + 1];

    // ---- pool: 64 rowgroups (8/wave) x 8 chunks of ushort8 ----
    {
        const int w = t >> 6, lane = t & 63;
        const int rg = w * 8 + (lane >> 3);
        const int sub = lane & 7;
        float acc[8];
#pragma unroll
        for (int j = 0; j < 8; j++) acc[j] = 0.f;
        for (int i = gs + rg; i < ge; i += 64) {
            u16x8 v = *(const u16x8*)(xbuf + (size_t)i * 64 + sub * 8);
#pragma unroll
            for (int j = 0; j < 8; j++) acc[j] += bf2f(v[j]);
        }
#pragma unroll
        for (int off = 8; off <= 32; off <<= 1) {
#pragma unroll
            for (int j = 0; j < 8; j++) acc[j] += __shfl_xor(acc[j], off, 64);
        }
        if (lane < 8) {
#pragma unroll
            for (int j = 0; j < 8; j++) red2[w][lane * 8 + j] = acc[j];
        }
    }
    __syncthreads();
    {
        float cdiv = fmaxf((float)(ge - gs), 1.f);
        if (t < 64) {
            float s = 0.f;
#pragma unroll
            for (int w = 0; w < 8; w++) s += red2[w][t];
            comb[t] = s / cdiv;
        } else if (t < 192) {
            comb[t] = obs[b * 128 + (t - 64)];
        }
    }
    __syncthreads();

    const int t256 = t & 255;
    const int khalf = t >> 8;

    // ---- fc1: k split 2x96 ----
    {
        float accA = 0.f, accB = 0.f;
        int k0 = khalf * 96;
#pragma unroll 4
        for (int k = k0; k < k0 + 96; k += 2) {
            accA += comb[k] * Ws1[k * 256 + t256];
            accB += comb[k + 1] * Ws1[(k + 1) * 256 + t256];
        }
        red[t] = accA + accB;
    }
    __syncthreads();
    float acc = 0.f;
    if (t < 256) acc = bs1[t] + red[t] + red[t + 256];
    __syncthreads();

    // ---- LayerNorm over 256 ----
    red[t] = (t < 256) ? acc : 0.f;
    __syncthreads();
    for (int off = 128; off; off >>= 1) {
        if (t < off) red[t] += red[t + off];
        __syncthreads();
    }
    float mu = red[0] / 256.f;
    __syncthreads();
    float d = acc - mu;
    red[t] = (t < 256) ? d * d : 0.f;
    __syncthreads();
    for (int off = 128; off; off >>= 1) {
        if (t < off) red[t] += red[t + off];
        __syncthreads();
    }
    float var = red[0] / 256.f;
    if (t < 256) {
        float hn = d * rsqrtf(var + 1e-5f) * ln_g[t] + ln_b[t];
        hs[t] = hn > 0.f ? hn : 0.f;
    }
    __syncthreads();

    // ---- fc2: k split 2x128 ----
    {
        float a2A = 0.f, a2B = 0.f;
        int k0 = khalf * 128;
#pragma unroll 4
        for (int k = k0; k < k0 + 128; k += 2) {
            a2A += hs[k] * Ws2[k * 256 + t256];
            a2B += hs[k + 1] * Ws2[(k + 1) * 256 + t256];
        }
        red[t] = a2A + a2B;
    }
    __syncthreads();
    float acc2 = 0.f;
    if (t < 256) {
        acc2 = bs2[t] + red[t] + red[t + 256];
        acc2 = acc2 > 0.f ? acc2 : 0.f;
    }
    __syncthreads();
    if (t < 256) hs[t] = acc2;
    __syncthreads();

    // ---- logits: 16 outs x 32 k-chunks of 8 + LDS tree ----
    {
        int o = t & 15, ck = t >> 4;
        float p = 0.f;
#pragma unroll
        for (int k = 0; k < 8; k++)
            p += hs[ck * 8 + k] * Wa[(ck * 8 + k) * 16 + o];
        red[t] = p;
    }
    __syncthreads();
    for (int off = 16; off >= 1; off >>= 1) {
        if ((t >> 4) < off) red[t] += red[t + off * 16];
        __syncthreads();
    }
    if (t < 16) out_logits[b * 16 + t] = red[t] + ba[t];
    __syncthreads();

    // ---- value: full-width dot + tree over 512 ----
    red[t] = (t < 256) ? hs[t] * Wc[t] : 0.f;
    __syncthreads();
    for (int off = 256; off; off >>= 1) {
        if (t < off) red[t] += red[t + off];
        __syncthreads();
    }
    if (t == 0) out_value[b] = red[0] + bc[0];
}

// ---------------------------------------------------------------------------

extern "C" void kernel_launch(void* const* d_in, const int* in_sizes, int n_in,
                              void* d_out, int out_size, void* d_ws, size_t ws_size,
                              hipStream_t stream) {
    const float* obs    = (const float*)d_in[0];
    const float* nf     = (const float*)d_in[1];
    const int*   ei     = (const int*)d_in[2];
    const int*   batch  = (const int*)d_in[3];
    const float* W0     = (const float*)d_in[4];
    const float* a_src0 = (const float*)d_in[5];
    const float* a_dst0 = (const float*)d_in[6];
    const float* b0     = (const float*)d_in[7];
    const float* W1     = (const float*)d_in[8];
    const float* a_src1 = (const float*)d_in[9];
    const float* a_dst1 = (const float*)d_in[10];
    const float* b1     = (const float*)d_in[11];
    const float* W2     = (const float*)d_in[12];
    const float* a_src2 = (const float*)d_in[13];
    const float* a_dst2 = (const float*)d_in[14];
    const float* b2     = (const float*)d_in[15];
    const float* Ws1    = (const float*)d_in[16];
    const float* bs1    = (const float*)d_in[17];
    const float* ln_g   = (const float*)d_in[18];
    const float* ln_b   = (const float*)d_in[19];
    const float* Ws2    = (const float*)d_in[20];
    const float* bs2    = (const float*)d_in[21];
    const float* Wa     = (const float*)d_in[22];
    const float* ba     = (const float*)d_in[23];
    const float* Wc     = (const float*)d_in[24];
    const float* bc     = (const float*)d_in[25];

    const int N = in_sizes[3];
    const int E = in_sizes[2] / 2;
    const int B = in_sizes[0] / 128;
    const int* src = ei;
    const int* dstp = ei + E;

    // workspace carve (256B aligned)
    char* p = (char*)d_ws;
    auto alloc = [&](size_t bytes) -> void* {
        void* r = (void*)p;
        p += (bytes + 255) & ~(size_t)255;
        return r;
    };
    const int G1 = (E + 2047) / 2048;       // edge chunks (2048/block)
    const int NB = (N + 255) >> 8;          // dst buckets of 256 (n <= 65536)
    const int L  = NB * G1;                 // histT length
    int*   row_ptr   = (int*)alloc((size_t)(N + 1) * 4);
    int*   col       = (int*)alloc((size_t)E * 4);
    int*   esrc      = (int*)alloc((size_t)E * 4);           // bucketed src
    unsigned char* dsub8 = (unsigned char*)alloc((size_t)E); // bucketed dst&255
    int*   histT     = (int*)alloc((size_t)L * 4);           // [b][g]
    int*   offs      = (int*)alloc((size_t)(L + 1) * 4);
    unsigned char* hbufA = (unsigned char*)alloc((size_t)N * 128);  // fp8 ping
    unsigned char* hbufB = (unsigned char*)alloc((size_t)N * 128);  // fp8 pong
    unsigned short* xbuf = (unsigned short*)alloc((size_t)N * 64 * 2);  // bf16
    float* as0       = (float*)alloc((size_t)N * 2 * 4);
    float* ad0       = (float*)alloc((size_t)N * 2 * 4);
    float* as1       = (float*)alloc((size_t)N * 2 * 4);
    float* ad1       = (float*)alloc((size_t)N * 2 * 4);
    float* as2v      = (float*)alloc((size_t)N * 4);
    float* ad2v      = (float*)alloc((size_t)N * 4);
    unsigned short* Wf1 = (unsigned short*)alloc((size_t)8 * 4 * 64 * 8 * 2);
    unsigned short* Wf2 = (unsigned short*)alloc((size_t)4 * 4 * 64 * 8 * 2);
    int* gstart      = (int*)alloc((size_t)(B + 1) * 4);
    int* blockSums   = (int*)alloc((size_t)1024 * 4);

    float* out_logits = (float*)d_out;
    float* out_value  = out_logits + (size_t)B * 16;

    // ---- P1: hist || transform0 || W pack || gstart (1 dispatch) ----
    int t0_blocks = (N + 15) / 16;
    int wp_blocks = (8 * 4 * 64 + 4 * 4 * 64 + 255) / 256;
    int gb_blocks = (N + 255) / 256;
    hist_t0_kernel<<<G1 + t0_blocks + wp_blocks + gb_blocks, 256, 0, stream>>>(
        dstp, histT, E, G1, NB, N, G1, t0_blocks, wp_blocks,
        nf, W0, a_src0, a_dst0, hbufA, as0, ad0,
        W1, W2, Wf1, Wf2, batch, gstart, B);

    // ---- scanA over histT -> offs (2 small dispatches) ----
    int nbA = (L + 511) / 512;
    scan2_block_kernel<<<nbA, 256, 0, stream>>>(histT, offs, blockSums, L);
    scan2_finalize_kernel<<<(L + 1 + 511) / 512, 256, 0, stream>>>(offs, blockSums, L, nbA);

    // ---- P3 bucket partition (LDS-cached offs col) + P4 finalize ----
    bucket_scatter_kernel<<<G1, 256, 0, stream>>>(src, dstp, offs, esrc, dsub8, E, G1, NB);
    bucket_csr_kernel<<<NB, 256, 0, stream>>>(offs, dsub8, esrc, row_ptr, col, G1, N);

    // ---- GAT layer 0 agg + fused transform1 (hA,as0 -> hB,as1) ----
    agg2t_kernel<128, 2><<<(N + 15) / 16, 512, 0, stream>>>(
        row_ptr, col, hbufA, (const float2*)as0, (const float2*)ad0, b0,
        Wf1, a_src1, a_dst1, hbufB, as1, ad1, N);

    // ---- GAT layer 1 agg + fused transform2 (hB,as1 -> hA,as2) ----
    agg2t_kernel<64, 1><<<(N + 15) / 16, 512, 0, stream>>>(
        row_ptr, col, hbufB, (const float2*)as1, (const float2*)ad1, b1,
        Wf2, a_src2, a_dst2, hbufA, as2v, ad2v, N);

    // ---- GAT layer 2 aggregation -> xbuf ----
    agg1_kernel<<<(N + 7) / 8, 256, 0, stream>>>(
        row_ptr, col, hbufA, as2v, ad2v, b2, xbuf, N);

    // ---- MLP head with fused mean-pool (1 dispatch, no atomics) ----
    mlp_kernel<<<B, 512, 0, stream>>>(xbuf, gstart, obs, Ws1, bs1, ln_g, ln_b,
                                      Ws2, bs2, Wa, ba, Wc, bc,
                                      out_logits, out_value);
}